// Round 13
// baseline (282.436 us; speedup 1.0000x reference)
//
#include <hip/hip_runtime.h>

#define B_   8
#define C_   128
#define N_   4096
#define C2_  64

typedef __bf16 bf16x8 __attribute__((ext_vector_type(8)));
typedef float  f32x4  __attribute__((ext_vector_type(4)));

#define MFMA16(a, b, c) __builtin_amdgcn_mfma_f32_16x16x32_bf16((a), (b), (c), 0, 0, 0)

// sqrt(log2(e)): folded into w_qk by k0 so softmax uses exp2 directly
#define QK_SCALE 1.2011224087864498f

static __device__ __forceinline__ unsigned short f2bf(float f) {
    union { __bf16 b; unsigned short u; } cv;
    cv.b = (__bf16)f;
    return cv.u;
}
static __device__ __forceinline__ float bf2f(unsigned short u) {
    union { unsigned int u; float f; } cv;
    cv.u = ((unsigned int)u) << 16;
    return cv.f;
}

struct us4 { unsigned short a, b, c, d; };

// async global->LDS, 16 B per lane.  LDS dest must be linear in lane order.
static __device__ __forceinline__ void gl_lds16(const unsigned short* g, void* l) {
    __builtin_amdgcn_global_load_lds(
        (const __attribute__((address_space(1))) unsigned int*)g,
        (__attribute__((address_space(3))) unsigned int*)l,
        16, 0, 0);
}

// ---------------------------------------------------------------------------
// K0: one-time weight convert f32 -> bf16, stacked [w_qk; w_v; w_x] = [192][128]
//     (QK_SCALE folded into w_qk rows) + zero bn[128] for k4's atomics.
// ---------------------------------------------------------------------------
__global__ __launch_bounds__(256) void k0_wcvt(
    const float* __restrict__ wq, const float* __restrict__ wv,
    const float* __restrict__ wx, unsigned short* __restrict__ wst,
    float* __restrict__ bn)
{
    if (blockIdx.x == 0 && threadIdx.x < 128) bn[threadIdx.x] = 0.f;
    const int i4 = (blockIdx.x * 256 + threadIdx.x) * 4;   // [0, 24576)
    const int mat = i4 >> 13;                              // 8192 elems / matrix
    const float* src = (mat == 0) ? wq : (mat == 1) ? wv : wx;
    const float sc = (mat == 0) ? QK_SCALE : 1.0f;
    const float4 v = *(const float4*)(src + (i4 & 8191));
    us4 pk;
    pk.a = f2bf(v.x * sc); pk.b = f2bf(v.y * sc);
    pk.c = f2bf(v.z * sc); pk.d = f2bf(v.w * sc);
    *(us4*)(wst + i4) = pk;
}

// ---------------------------------------------------------------------------
// K1: fused projection GEMM.  D[192 o][64 n] = Wst[o][c] * x[c][n] per
//     (b, 64-n tile).  Weights (bf16 from k0) DMA-staged XOR-swizzled ->
//     LDS [192][128]; x tile transposed -> LDS bf16 x_t[64 n][136 c].
//     Epilogue: ot 0-3 -> qk_t; ot 4-7 -> xv_bf (+b_v); ot 8-11 -> xc (BF16).
// ---------------------------------------------------------------------------
__global__ __launch_bounds__(256) void k1_proj(
    const float* __restrict__ x, const unsigned short* __restrict__ wst,
    const float* __restrict__ b_v,
    unsigned short* __restrict__ qk_t, unsigned short* __restrict__ xv_bf,
    unsigned short* __restrict__ xc_bf)
{
    __shared__ __align__(16) unsigned short w_lds[192 * 128];
    __shared__ __align__(16) unsigned short x_t[64 * 136];
    const int tid = threadIdx.x;
    const int wave = tid >> 6, lane = tid & 63;
    const int quad = lane >> 4, col = lane & 15;
    const int b = blockIdx.y;
    const int n0 = blockIdx.x * 64;

    #pragma unroll
    for (int it = 0; it < 12; ++it) {
        const int idx = it * 256 + tid;                // [0, 3072)
        const int row = idx >> 4, seg = idx & 15;
        gl_lds16(wst + (size_t)row * 128 + (size_t)(seg ^ (row & 7)) * 8,
                 w_lds + idx * 8);
    }
    const float* xb = x + (size_t)b * C_ * N_ + n0;
    #pragma unroll
    for (int it = 0; it < 8; ++it) {
        const int idx = it * 256 + tid;                // [0, 2048)
        const int c = idx >> 4, n = (idx & 15) * 4;
        const float4 v = *(const float4*)(xb + (size_t)c * N_ + n);
        x_t[(n + 0) * 136 + c] = f2bf(v.x);
        x_t[(n + 1) * 136 + c] = f2bf(v.y);
        x_t[(n + 2) * 136 + c] = f2bf(v.z);
        x_t[(n + 3) * 136 + c] = f2bf(v.w);
    }
    __syncthreads();

    const int nw = wave * 16;
    bf16x8 bfr[4];
    #pragma unroll
    for (int kt = 0; kt < 4; ++kt)
        bfr[kt] = *(const bf16x8*)&x_t[(nw + col) * 136 + kt * 32 + quad * 8];

    const int n_g = n0 + nw + col;

    #pragma unroll
    for (int ot = 0; ot < 12; ++ot) {
        f32x4 acc = {0.f, 0.f, 0.f, 0.f};
        #pragma unroll
        for (int kt = 0; kt < 4; ++kt) {
            const bf16x8 afr = *(const bf16x8*)&w_lds[
                ((ot * 16 + col) << 7) + (((kt * 4 + quad) ^ (col & 7)) << 3)];
            acc = MFMA16(afr, bfr[kt], acc);
        }
        if (ot < 4) {
            us4 pk;
            pk.a = f2bf(acc[0]); pk.b = f2bf(acc[1]);
            pk.c = f2bf(acc[2]); pk.d = f2bf(acc[3]);
            *(us4*)&qk_t[(size_t)(b * N_ + n_g) * C2_ + ot * 16 + quad * 4] = pk;
        } else if (ot < 8) {
            const float4 bv4 = *(const float4*)(b_v + (ot - 4) * 16 + quad * 4);
            const float* bvp = (const float*)&bv4;
            #pragma unroll
            for (int r = 0; r < 4; ++r)
                xv_bf[(size_t)(b * C2_ + (ot - 4) * 16 + quad * 4 + r) * N_ + n_g]
                    = f2bf(acc[r] + bvp[r]);
        } else {
            #pragma unroll
            for (int r = 0; r < 4; ++r)
                xc_bf[(size_t)(b * C2_ + (ot - 8) * 16 + quad * 4 + r) * N_ + n_g]
                    = f2bf(acc[r]);
        }
    }
}

// ---------------------------------------------------------------------------
// K2_sym: partial row softmax sums exploiting E symmetry (E[n][m]=E[m][n]
//     since q,k share w_qk).  Only tiles ti<=tj computed: 528/1024 = 51.6%
//     of E-GEMM+exp2.  Off-diag tile (ti,tj): row sums -> range ti slot tj,
//     col sums -> range tj slot ti; diag: rows only.  Every (slot,range)
//     written once -> no atomics.  part_rs[32][8][4096].  Grid 4224.
// ---------------------------------------------------------------------------
__global__ __launch_bounds__(256) void k2_sym(
    const unsigned short* __restrict__ qk_t, float* __restrict__ part_rs)
{
    __shared__ __align__(16) unsigned short slab[128 * 64];
    __shared__ float cwl[4 * 128];
    const int tid = threadIdx.x;
    const int wave = tid >> 6, lane = tid & 63;
    const int quad = lane >> 4, col = lane & 15;
    const int b = blockIdx.x & 7;
    int job = blockIdx.x >> 3, ti = 0;                 // job in [0,528)
    while (job >= 32 - ti) { job -= 32 - ti; ++ti; }
    const int tj = ti + job;
    const unsigned short* qb = qk_t + (size_t)b * N_ * C2_;

    const int n_base = ti * 128 + wave * 32;
    bf16x8 a0[2], a1[2];
    #pragma unroll
    for (int s = 0; s < 2; ++s) {
        const unsigned short* p = qb + (size_t)(n_base + s * 16 + col) * C2_ + quad * 8;
        a0[s] = *(const bf16x8*)p;
        a1[s] = *(const bf16x8*)(p + 32);
    }

    #pragma unroll
    for (int r = 0; r < 4; ++r) {
        const int idx = r * 256 + tid;                 // [0, 1024)
        const int row = idx >> 3, seg = idx & 7;
        gl_lds16(qb + (size_t)(tj * 128 + row) * C2_ + (size_t)(seg ^ (row & 7)) * 8,
                 slab + idx * 8);
    }
    __syncthreads();

    float run_s[2][4];
    #pragma unroll
    for (int s = 0; s < 2; ++s)
        #pragma unroll
        for (int r = 0; r < 4; ++r) run_s[s][r] = 0.f;

    #pragma unroll
    for (int g = 0; g < 8; ++g) {
        const int row = g * 16 + col;
        const bf16x8 b0 = *(const bf16x8*)(slab + row * 64 + ((quad ^ (col & 7)) * 8));
        const bf16x8 b1 = *(const bf16x8*)(slab + row * 64 + (((4 + quad) ^ (col & 7)) * 8));
        float cs = 0.f;
        #pragma unroll
        for (int s = 0; s < 2; ++s) {
            f32x4 acc = {0.f, 0.f, 0.f, 0.f};
            __builtin_amdgcn_s_setprio(1);
            acc = MFMA16(a0[s], b0, acc);
            acc = MFMA16(a1[s], b1, acc);
            __builtin_amdgcn_s_setprio(0);
            #pragma unroll
            for (int r = 0; r < 4; ++r) {
                const float u = __builtin_amdgcn_exp2f(acc[r]);
                run_s[s][r] += u;
                cs += u;
            }
        }
        cs += __shfl_xor(cs, 16, 64);
        cs += __shfl_xor(cs, 32, 64);
        if (quad == 0) cwl[wave * 128 + g * 16 + col] = cs;
    }
    __syncthreads();
    if (ti != tj && tid < 128) {
        const float c = cwl[tid] + cwl[128 + tid] + cwl[256 + tid] + cwl[384 + tid];
        part_rs[((size_t)(ti * 8 + b) << 12) + tj * 128 + tid] = c;
    }

    #pragma unroll
    for (int s = 0; s < 2; ++s)
        #pragma unroll
        for (int r = 0; r < 4; ++r) {
            #pragma unroll
            for (int off = 1; off < 16; off <<= 1)
                run_s[s][r] += __shfl_xor(run_s[s][r], off, 64);
        }
    if (col == 0) {
        #pragma unroll
        for (int s = 0; s < 2; ++s)
            #pragma unroll
            for (int r = 0; r < 4; ++r)
                part_rs[((size_t)(tj * 8 + b) << 12) + n_base + s * 16 + quad * 4 + r]
                    = run_s[s][r];
    }
}

// ---------------------------------------------------------------------------
// K2w: lw[b][n] = -log2( sum_{t<32} part_rs[t][b][n] ).  Grid 128 x 256.
// ---------------------------------------------------------------------------
__global__ __launch_bounds__(256) void k2w(
    const float* __restrict__ part_rs, float* __restrict__ lw)
{
    const int idx = blockIdx.x * 256 + threadIdx.x;    // [0, 32768)
    const int b = idx >> 12, n = idx & 4095;
    float s = 0.f;
    #pragma unroll
    for (int t = 0; t < 32; ++t)
        s += part_rs[((size_t)(t * 8 + b) << 12) + n];
    lw[b * N_ + n] = -__log2f(s);
}

// ---------------------------------------------------------------------------
// K3: R7 structure + lw via MFMA C-operand (prefetched one chunk ahead;
//     R11 lesson: at-use loads sit in the E serial chain).  S'' = exp2(E+lw);
//     PV uses raw xv; colsum A = ones.  DMA dbuf staging, 1 barrier/chunk,
//     wave-private stS with stride 42 (R12: stride 40 -> dword-stride 20,
//     col/col+8 bank alias on every S' write; 21 coprime 32 -> all 16 cols
//     distinct banks).  8 waves, 32-m/wave, split-K=2, grid 512 = 2 blk/CU.
//     launch_bounds(512,4): cap 128 >> natural ~110 -> no spill.
// ---------------------------------------------------------------------------
__global__ __launch_bounds__(512, 4) void k3_pv(
    const unsigned short* __restrict__ qk_t, const unsigned short* __restrict__ xv_bf,
    const float* __restrict__ lw,
    unsigned short* __restrict__ yb0, unsigned short* __restrict__ yb1,
    float* __restrict__ cspart)
{
    // 0..16K: qk dbuf | 16K..32K: xv dbuf | 32K..53K: stS (8 waves x 2688 B)
    __shared__ __align__(16) unsigned char lds_raw[32768 + 8 * 2688];
    const int tid = threadIdx.x;
    const int wave = tid >> 6, lane = tid & 63;
    const int quad = lane >> 4, col = lane & 15;
    const int nh2 = wave & 1, mh = wave >> 1;        // mh 0..3
    const int b = blockIdx.x & 7;
    const int m_blk = ((blockIdx.x >> 3) & 31) * 128;
    const int sk = blockIdx.x >> 8;                  // 0..1 (split-K index)
    const int n_start = sk * 2048;
    const int n_chunks = 32;
    const int m_wave = m_blk + mh * 32;
    const unsigned short* qb = qk_t + (size_t)b * N_ * C2_;
    const unsigned short* vb = xv_bf + (size_t)b * C2_ * N_;
    const float* ln = lw + b * N_;
    unsigned short* yp = (sk == 0) ? yb0 : yb1;

    // persistent B-operands for E: this wave's 32 m-cols (2 groups of 16)
    bf16x8 kb0[2], kb1[2];
    #pragma unroll
    for (int g = 0; g < 2; ++g) {
        const unsigned short* p = qb + (size_t)(m_wave + g * 16 + col) * C2_ + quad * 8;
        kb0[g] = *(const bf16x8*)p;
        kb1[g] = *(const bf16x8*)(p + 32);
    }

    // colsum A-operand: constant ones (S'' already carries the row scale)
    bf16x8 ones;
    #pragma unroll
    for (int j = 0; j < 8; ++j) ones[j] = (__bf16)1.0f;

    unsigned short* stS = (unsigned short*)(lds_raw + 32768 + wave * 2688); // [g][col][42]

    // stage one 64n qk slab + 64ch xv tile (8 KB each): 1 DMA/lane/array
    auto stage = [&](int n0, int p) {
        unsigned char* qbase = lds_raw + p * 8192;
        unsigned char* vbase = lds_raw + 16384 + p * 8192;
        const int row = tid >> 3, seg = tid & 7;
        const int ss = seg ^ (row & 7);
        gl_lds16(qb + (size_t)(n0 + row) * C2_ + (size_t)ss * 8, qbase + tid * 16);
        gl_lds16(vb + (size_t)row * N_ + n0 + ss * 8, vbase + tid * 16);
    };

    f32x4 accY[2][4];   // [g][os]
    #pragma unroll
    for (int g = 0; g < 2; ++g)
        #pragma unroll
        for (int os = 0; os < 4; ++os) accY[g][os] = (f32x4){0.f, 0.f, 0.f, 0.f};
    f32x4 csacc[2];
    #pragma unroll
    for (int g = 0; g < 2; ++g) csacc[g] = (f32x4){0.f, 0.f, 0.f, 0.f};

    // lw prefetch: this wave's 8 lw values per chunk (ns=0/1), one chunk ahead
    const float* lwp = ln + n_start + nh2 * 32 + quad * 4;
    float4 lwA = *(const float4*)(lwp);         // chunk 0, ns=0
    float4 lwB = *(const float4*)(lwp + 16);    // chunk 0, ns=1

    stage(n_start, 0);
    __syncthreads();

    for (int c = 0; c < n_chunks; ++c) {
        const int n0 = n_start + c * 64;
        const int p = c & 1;
        if (c + 1 < n_chunks) stage(n0 + 64, 1 - p);

        const unsigned short* qt = (const unsigned short*)(lds_raw + p * 8192);
        const unsigned short* vt = (const unsigned short*)(lds_raw + 16384 + p * 8192);

        // E phase; S'' = exp2(E + lw[n]) -> LDS (lw enters as MFMA C-init,
        // prefetched last chunk -> off the serial chain)
        #pragma unroll
        for (int ns = 0; ns < 2; ++ns) {
            const int row = nh2 * 32 + ns * 16 + col;
            const bf16x8 qa0 = *(const bf16x8*)(qt + row * 64 + ((quad ^ (col & 7)) * 8));
            const bf16x8 qa1 = *(const bf16x8*)(qt + row * 64 + (((4 + quad) ^ (col & 7)) * 8));
            const float4 lw4 = ns ? lwB : lwA;
            #pragma unroll
            for (int g = 0; g < 2; ++g) {
                f32x4 acc = {lw4.x, lw4.y, lw4.z, lw4.w};
                acc = MFMA16(qa0, kb0[g], acc);
                acc = MFMA16(qa1, kb1[g], acc);
                union { unsigned short us[4]; uint2 u2; } pk;
                #pragma unroll
                for (int r = 0; r < 4; ++r)
                    pk.us[r] = f2bf(__builtin_amdgcn_exp2f(acc[r]));
                *(uint2*)&stS[(g * 16 + col) * 42 + ns * 16 + quad * 4] = pk.u2;
            }
        }

        // prefetch lw for next chunk (covered by PV below)
        if (c + 1 < n_chunks) {
            lwA = *(const float4*)(lwp + (c + 1) * 64);
            lwB = *(const float4*)(lwp + (c + 1) * 64 + 16);
        }

        // same-wave round-trip: S'' as B-operand (K = this wave's 32 n)
        bf16x8 sB[2];
        #pragma unroll
        for (int g = 0; g < 2; ++g)
            sB[g] = *(const bf16x8*)&stS[(g * 16 + col) * 42 + quad * 8];

        // colsum via MFMA with A = ones -> D rows all = colsum of S''
        #pragma unroll
        for (int g = 0; g < 2; ++g)
            csacc[g] = MFMA16(ones, sB[g], csacc[g]);

        // PV: A = raw xv rows (o), k = this wave's 32 n
        #pragma unroll
        for (int os = 0; os < 4; ++os) {
            const bf16x8 va = *(const bf16x8*)(vt + (os * 16 + col) * 64 +
                                               (((nh2 * 4 + quad) ^ (col & 7)) * 8));
            #pragma unroll
            for (int g = 0; g < 2; ++g)
                accY[g][os] = MFMA16(va, sB[g], accY[g][os]);
        }
        __syncthreads();
    }

    // epilogue: combine the two n-halves (waves nh2=1 -> LDS; nh2=0 adds+writes)
    float* cmb = (float*)lds_raw;              // 32 KB: [mh][g*4+os][r][lane]
    float* csc = (float*)(lds_raw + 32768);    // 2 KB:  [mh][g][lane]
    if (nh2 == 1) {
        #pragma unroll
        for (int g = 0; g < 2; ++g) {
            #pragma unroll
            for (int os = 0; os < 4; ++os)
                #pragma unroll
                for (int r = 0; r < 4; ++r)
                    cmb[((mh * 8 + g * 4 + os) * 4 + r) * 64 + lane] = accY[g][os][r];
            csc[(mh * 2 + g) * 64 + lane] = csacc[g][0];
        }
    }
    __syncthreads();
    if (nh2 == 0) {
        #pragma unroll
        for (int g = 0; g < 2; ++g) {
            const float cs = csacc[g][0] + csc[(mh * 2 + g) * 64 + lane];
            if (lane < 16)
                cspart[((size_t)sk * 8 + b) * N_ + m_wave + g * 16 + lane] = cs;
            #pragma unroll
            for (int os = 0; os < 4; ++os)
                #pragma unroll
                for (int r = 0; r < 4; ++r) {
                    const float v = accY[g][os][r] +
                        cmb[((mh * 8 + g * 4 + os) * 4 + r) * 64 + lane];
                    yp[(size_t)(b * C2_ + os * 16 + quad * 4 + r) * N_ + m_wave + g * 16 + col]
                        = f2bf(v);
                }
        }
    }
}

// ---------------------------------------------------------------------------
// K4: fused partial-combine + w_t GEMM (MFMA) + BN stats via GLOBAL ATOMICS
//     (replaces part_bn + k5r; bn zeroed by k0, stream-ordered).
//     Grid (64, 8).  cinv = 1/(eps+sum cspart); d = xc - (y0+y1)*cinv
//     staged TRANSPOSED to LDS bf16 d_t[n][72]; w_t [o][72].  Wave = o-tile;
//     K=64.  t -> t_bf (BF16; stats from unrounded f32).
// ---------------------------------------------------------------------------
__global__ __launch_bounds__(256) void k4_t(
    const unsigned short* __restrict__ xc_bf, const unsigned short* __restrict__ y0,
    const unsigned short* __restrict__ y1,
    const float* __restrict__ cspart, const float* __restrict__ w_t,
    const float* __restrict__ b_t, unsigned short* __restrict__ t_bf,
    float* __restrict__ bn)
{
    __shared__ __align__(16) unsigned short wlds[64 * 72];
    __shared__ __align__(16) unsigned short d_t[64 * 72];
    __shared__ float cinv[64];
    const int tid = threadIdx.x;
    const int wave = tid >> 6, lane = tid & 63;
    const int quad = lane >> 4, col = lane & 15;
    const int b = blockIdx.y;
    const int n0 = blockIdx.x * 64;
    const size_t base = (size_t)b * C2_ * N_;

    #pragma unroll
    for (int it = 0; it < 4; ++it) {
        const int idx4 = it * 256 + tid;               // [0, 1024)
        const int o = idx4 >> 4, i4 = (idx4 & 15) * 4;
        const float4 v = *(const float4*)(w_t + o * 64 + i4);
        us4 pk;
        pk.a = f2bf(v.x); pk.b = f2bf(v.y); pk.c = f2bf(v.z); pk.d = f2bf(v.w);
        *(us4*)&wlds[o * 72 + i4] = pk;
    }
    if (tid < 64) {
        const int n = n0 + tid;
        const float cs = cspart[(size_t)b * N_ + n] + cspart[(size_t)(8 + b) * N_ + n];
        cinv[tid] = 1.0f / (1e-9f + cs);
    }
    __syncthreads();

    #pragma unroll
    for (int it = 0; it < 4; ++it) {
        const int idx4 = it * 256 + tid;               // [0, 1024)
        const int i = idx4 >> 4, n4 = (idx4 & 15) * 4;
        const size_t g = base + (size_t)i * N_ + n0 + n4;
        const us4 cx = *(const us4*)(xc_bf + g);
        const us4 u0 = *(const us4*)(y0 + g);
        const us4 u1 = *(const us4*)(y1 + g);
        d_t[(n4 + 0) * 72 + i] = f2bf(bf2f(cx.a) - (bf2f(u0.a) + bf2f(u1.a)) * cinv[n4 + 0]);
        d_t[(n4 + 1) * 72 + i] = f2bf(bf2f(cx.b) - (bf2f(u0.b) + bf2f(u1.b)) * cinv[n4 + 1]);
        d_t[(n4 + 2) * 72 + i] = f2bf(bf2f(cx.c) - (bf2f(u0.c) + bf2f(u1.c)) * cinv[n4 + 2]);
        d_t[(n4 + 3) * 72 + i] = f2bf(bf2f(cx.d) - (bf2f(u0.d) + bf2f(u1.d)) * cinv[n4 + 3]);
    }
    __syncthreads();

    const int ow = wave * 16;
    bf16x8 afr[2];
    #pragma unroll
    for (int kt = 0; kt < 2; ++kt)
        afr[kt] = *(const bf16x8*)&wlds[(ow + col) * 72 + kt * 32 + quad * 8];
    const float4 bt4 = *(const float4*)(b_t + ow + quad * 4);
    const float* btp = (const float*)&bt4;

    float s[4] = {0.f, 0.f, 0.f, 0.f}, q2[4] = {0.f, 0.f, 0.f, 0.f};
    #pragma unroll
    for (int ns = 0; ns < 4; ++ns) {
        f32x4 acc = {0.f, 0.f, 0.f, 0.f};
        #pragma unroll
        for (int kt = 0; kt < 2; ++kt) {
            const bf16x8 bfr = *(const bf16x8*)&d_t[(ns * 16 + col) * 72 + kt * 32 + quad * 8];
            acc = MFMA16(afr[kt], bfr, acc);
        }
        #pragma unroll
        for (int r = 0; r < 4; ++r) {
            const float t = acc[r] + btp[r];
            t_bf[base + (size_t)(ow + quad * 4 + r) * N_ + n0 + ns * 16 + col] = f2bf(t);
            s[r] += t;
            q2[r] += t * t;
        }
    }
    #pragma unroll
    for (int r = 0; r < 4; ++r) {
        #pragma unroll
        for (int off = 1; off < 16; off <<= 1) {
            s[r]  += __shfl_xor(s[r],  off, 64);
            q2[r] += __shfl_xor(q2[r], off, 64);
        }
    }
    if (col == 0) {
        #pragma unroll
        for (int r = 0; r < 4; ++r) {
            atomicAdd(&bn[ow + quad * 4 + r], s[r]);
            atomicAdd(&bn[64 + ow + quad * 4 + r], q2[r]);
        }
    }
}

// ---------------------------------------------------------------------------
// K6: out = xc + relu(gamma * (t - mean) * rsqrt(var + eps) + beta)
//     xc, t read as BF16 (us4); out written f32.
// ---------------------------------------------------------------------------
__global__ __launch_bounds__(256) void k6_out(
    const unsigned short* __restrict__ xc_bf, const unsigned short* __restrict__ t_bf,
    const float* __restrict__ bn, const float* __restrict__ gamma,
    const float* __restrict__ beta, float* __restrict__ out)
{
    const int idx = blockIdx.x * 256 + threadIdx.x;
    const int o = (idx >> 10) & 63;
    const float invC = 1.0f / (float)(B_ * N_);
    const float mean = bn[o] * invC;
    const float var  = bn[64 + o] * invC - mean * mean;
    const float sc = gamma[o] * rsqrtf(var + 1e-5f);
    const float sh = beta[o] - mean * sc;
    const us4 t4 = ((const us4*)t_bf)[idx];
    const us4 c4 = ((const us4*)xc_bf)[idx];
    float4 r;
    r.x = bf2f(c4.a) + fmaxf(0.f, sc * bf2f(t4.a) + sh);
    r.y = bf2f(c4.b) + fmaxf(0.f, sc * bf2f(t4.b) + sh);
    r.z = bf2f(c4.c) + fmaxf(0.f, sc * bf2f(t4.c) + sh);
    r.w = bf2f(c4.d) + fmaxf(0.f, sc * bf2f(t4.d) + sh);
    ((float4*)out)[idx] = r;
}

extern "C" void kernel_launch(void* const* d_in, const int* in_sizes, int n_in,
                              void* d_out, int out_size, void* d_ws, size_t ws_size,
                              hipStream_t stream) {
    const float* x     = (const float*)d_in[0];
    const float* w_qk  = (const float*)d_in[1];
    const float* w_v   = (const float*)d_in[2];
    const float* b_v   = (const float*)d_in[3];
    const float* w_x   = (const float*)d_in[4];
    const float* w_t   = (const float*)d_in[5];
    const float* b_t   = (const float*)d_in[6];
    const float* gamma = (const float*)d_in[7];
    const float* beta  = (const float*)d_in[8];
    float* out = (float*)d_out;

    char* ws = (char*)d_ws;
    unsigned short* qk_t  = (unsigned short*)ws;                      // 4 MB
    unsigned short* xv_bf = (unsigned short*)(ws + (4  << 20));       // 4 MB
    unsigned short* xc_bf = (unsigned short*)(ws + (8  << 20));       // 4 MB (bf16)
    unsigned short* t_bf  = (unsigned short*)(ws + (12 << 20));       // 4 MB (bf16)
    unsigned short* yb0 = (unsigned short*)(ws + (16 << 20));         // 4 MB (bf16 partial Y)
    unsigned short* yb1 = (unsigned short*)(ws + (20 << 20));         // 4 MB (bf16 partial Y)
    float* part_rs = (float*)(ws + (24 << 20));                       // 4 MB (k2_sym -> k2w)
    float* cspart  = (float*)(ws + (32 << 20));                       // 256 KB (k3 -> k4)
    float* bn      = (float*)(ws + (33 << 20));                       // 512 B (k4 atomics)
    // d_out doubles as scratch until k6 (k6 is the only writer of out):
    unsigned short* wstack = (unsigned short*)d_out;                  // 48 KB (k0 -> k1)
    float* lw = (float*)((char*)d_out + (256 << 10));                 // 128 KB (k2w -> k3)

    hipLaunchKernelGGL(k0_wcvt,     dim3(24),     256, 0, stream, w_qk, w_v, w_x, wstack, bn);
    hipLaunchKernelGGL(k1_proj,     dim3(64, 8),  256, 0, stream,
                       x, wstack, b_v, qk_t, xv_bf, xc_bf);
    hipLaunchKernelGGL(k2_sym,      dim3(4224),   256, 0, stream, qk_t, part_rs);
    hipLaunchKernelGGL(k2w,         dim3(128),    256, 0, stream, part_rs, lw);
    hipLaunchKernelGGL(k3_pv,       dim3(512),    512, 0, stream,
                       qk_t, xv_bf, lw, yb0, yb1, cspart);
    hipLaunchKernelGGL(k4_t,        dim3(64, 8),  256, 0, stream,
                       xc_bf, yb0, yb1, cspart, w_t, b_t, t_bf, bn);
    hipLaunchKernelGGL(k6_out,      dim3(2048),   256, 0, stream, xc_bf, t_bf, bn, gamma, beta, out);
}

// Round 14
// 211.685 us; speedup vs baseline: 1.3342x; 1.3342x over previous
//
#include <hip/hip_runtime.h>

#define B_   8
#define C_   128
#define N_   4096
#define C2_  64

typedef __bf16 bf16x8 __attribute__((ext_vector_type(8)));
typedef float  f32x4  __attribute__((ext_vector_type(4)));

#define MFMA16(a, b, c) __builtin_amdgcn_mfma_f32_16x16x32_bf16((a), (b), (c), 0, 0, 0)

// sqrt(log2(e)): folded into w_qk by k0 so softmax uses exp2 directly
#define QK_SCALE 1.2011224087864498f

static __device__ __forceinline__ unsigned short f2bf(float f) {
    union { __bf16 b; unsigned short u; } cv;
    cv.b = (__bf16)f;
    return cv.u;
}
static __device__ __forceinline__ float bf2f(unsigned short u) {
    union { unsigned int u; float f; } cv;
    cv.u = ((unsigned int)u) << 16;
    return cv.f;
}

struct us4 { unsigned short a, b, c, d; };

// async global->LDS, 16 B per lane.  LDS dest must be linear in lane order.
static __device__ __forceinline__ void gl_lds16(const unsigned short* g, void* l) {
    __builtin_amdgcn_global_load_lds(
        (const __attribute__((address_space(1))) unsigned int*)g,
        (__attribute__((address_space(3))) unsigned int*)l,
        16, 0, 0);
}

// ---------------------------------------------------------------------------
// K0: one-time weight convert f32 -> bf16, stacked [w_qk; w_v; w_x] = [192][128]
//     (QK_SCALE folded into w_qk rows) + zero bn[128] for k4's atomics.
// ---------------------------------------------------------------------------
__global__ __launch_bounds__(256) void k0_wcvt(
    const float* __restrict__ wq, const float* __restrict__ wv,
    const float* __restrict__ wx, unsigned short* __restrict__ wst,
    float* __restrict__ bn)
{
    if (blockIdx.x == 0 && threadIdx.x < 128) bn[threadIdx.x] = 0.f;
    const int i4 = (blockIdx.x * 256 + threadIdx.x) * 4;   // [0, 24576)
    const int mat = i4 >> 13;                              // 8192 elems / matrix
    const float* src = (mat == 0) ? wq : (mat == 1) ? wv : wx;
    const float sc = (mat == 0) ? QK_SCALE : 1.0f;
    const float4 v = *(const float4*)(src + (i4 & 8191));
    us4 pk;
    pk.a = f2bf(v.x * sc); pk.b = f2bf(v.y * sc);
    pk.c = f2bf(v.z * sc); pk.d = f2bf(v.w * sc);
    *(us4*)(wst + i4) = pk;
}

// ---------------------------------------------------------------------------
// K1: fused projection GEMM.  D[192 o][64 n] = Wst[o][c] * x[c][n] per
//     (b, 64-n tile).  Weights (bf16 from k0) DMA-staged XOR-swizzled ->
//     LDS [192][128]; x tile transposed -> LDS bf16 x_t[64 n][136 c].
//     Epilogue: ot 0-3 -> qk_t; ot 4-7 -> xv_bf (+b_v); ot 8-11 -> xc (BF16).
// ---------------------------------------------------------------------------
__global__ __launch_bounds__(256) void k1_proj(
    const float* __restrict__ x, const unsigned short* __restrict__ wst,
    const float* __restrict__ b_v,
    unsigned short* __restrict__ qk_t, unsigned short* __restrict__ xv_bf,
    unsigned short* __restrict__ xc_bf)
{
    __shared__ __align__(16) unsigned short w_lds[192 * 128];
    __shared__ __align__(16) unsigned short x_t[64 * 136];
    const int tid = threadIdx.x;
    const int wave = tid >> 6, lane = tid & 63;
    const int quad = lane >> 4, col = lane & 15;
    const int b = blockIdx.y;
    const int n0 = blockIdx.x * 64;

    #pragma unroll
    for (int it = 0; it < 12; ++it) {
        const int idx = it * 256 + tid;                // [0, 3072)
        const int row = idx >> 4, seg = idx & 15;
        gl_lds16(wst + (size_t)row * 128 + (size_t)(seg ^ (row & 7)) * 8,
                 w_lds + idx * 8);
    }
    const float* xb = x + (size_t)b * C_ * N_ + n0;
    #pragma unroll
    for (int it = 0; it < 8; ++it) {
        const int idx = it * 256 + tid;                // [0, 2048)
        const int c = idx >> 4, n = (idx & 15) * 4;
        const float4 v = *(const float4*)(xb + (size_t)c * N_ + n);
        x_t[(n + 0) * 136 + c] = f2bf(v.x);
        x_t[(n + 1) * 136 + c] = f2bf(v.y);
        x_t[(n + 2) * 136 + c] = f2bf(v.z);
        x_t[(n + 3) * 136 + c] = f2bf(v.w);
    }
    __syncthreads();

    const int nw = wave * 16;
    bf16x8 bfr[4];
    #pragma unroll
    for (int kt = 0; kt < 4; ++kt)
        bfr[kt] = *(const bf16x8*)&x_t[(nw + col) * 136 + kt * 32 + quad * 8];

    const int n_g = n0 + nw + col;

    #pragma unroll
    for (int ot = 0; ot < 12; ++ot) {
        f32x4 acc = {0.f, 0.f, 0.f, 0.f};
        #pragma unroll
        for (int kt = 0; kt < 4; ++kt) {
            const bf16x8 afr = *(const bf16x8*)&w_lds[
                ((ot * 16 + col) << 7) + (((kt * 4 + quad) ^ (col & 7)) << 3)];
            acc = MFMA16(afr, bfr[kt], acc);
        }
        if (ot < 4) {
            us4 pk;
            pk.a = f2bf(acc[0]); pk.b = f2bf(acc[1]);
            pk.c = f2bf(acc[2]); pk.d = f2bf(acc[3]);
            *(us4*)&qk_t[(size_t)(b * N_ + n_g) * C2_ + ot * 16 + quad * 4] = pk;
        } else if (ot < 8) {
            const float4 bv4 = *(const float4*)(b_v + (ot - 4) * 16 + quad * 4);
            const float* bvp = (const float*)&bv4;
            #pragma unroll
            for (int r = 0; r < 4; ++r)
                xv_bf[(size_t)(b * C2_ + (ot - 4) * 16 + quad * 4 + r) * N_ + n_g]
                    = f2bf(acc[r] + bvp[r]);
        } else {
            #pragma unroll
            for (int r = 0; r < 4; ++r)
                xc_bf[(size_t)(b * C2_ + (ot - 8) * 16 + quad * 4 + r) * N_ + n_g]
                    = f2bf(acc[r]);
        }
    }
}

// ---------------------------------------------------------------------------
// K2_sym: partial row softmax sums exploiting E symmetry (E[n][m]=E[m][n]
//     since q,k share w_qk).  Only tiles ti<=tj computed: 528/1024 = 51.6%
//     of E-GEMM+exp2.  Off-diag tile (ti,tj): row sums -> range ti slot tj,
//     col sums -> range tj slot ti; diag: rows only.  Every (slot,range)
//     written once -> no atomics.  part_rs[32][8][4096].  Grid 4224.
// ---------------------------------------------------------------------------
__global__ __launch_bounds__(256) void k2_sym(
    const unsigned short* __restrict__ qk_t, float* __restrict__ part_rs)
{
    __shared__ __align__(16) unsigned short slab[128 * 64];
    __shared__ float cwl[4 * 128];
    const int tid = threadIdx.x;
    const int wave = tid >> 6, lane = tid & 63;
    const int quad = lane >> 4, col = lane & 15;
    const int b = blockIdx.x & 7;
    int job = blockIdx.x >> 3, ti = 0;                 // job in [0,528)
    while (job >= 32 - ti) { job -= 32 - ti; ++ti; }
    const int tj = ti + job;
    const unsigned short* qb = qk_t + (size_t)b * N_ * C2_;

    const int n_base = ti * 128 + wave * 32;
    bf16x8 a0[2], a1[2];
    #pragma unroll
    for (int s = 0; s < 2; ++s) {
        const unsigned short* p = qb + (size_t)(n_base + s * 16 + col) * C2_ + quad * 8;
        a0[s] = *(const bf16x8*)p;
        a1[s] = *(const bf16x8*)(p + 32);
    }

    #pragma unroll
    for (int r = 0; r < 4; ++r) {
        const int idx = r * 256 + tid;                 // [0, 1024)
        const int row = idx >> 3, seg = idx & 7;
        gl_lds16(qb + (size_t)(tj * 128 + row) * C2_ + (size_t)(seg ^ (row & 7)) * 8,
                 slab + idx * 8);
    }
    __syncthreads();

    float run_s[2][4];
    #pragma unroll
    for (int s = 0; s < 2; ++s)
        #pragma unroll
        for (int r = 0; r < 4; ++r) run_s[s][r] = 0.f;

    #pragma unroll
    for (int g = 0; g < 8; ++g) {
        const int row = g * 16 + col;
        const bf16x8 b0 = *(const bf16x8*)(slab + row * 64 + ((quad ^ (col & 7)) * 8));
        const bf16x8 b1 = *(const bf16x8*)(slab + row * 64 + (((4 + quad) ^ (col & 7)) * 8));
        float cs = 0.f;
        #pragma unroll
        for (int s = 0; s < 2; ++s) {
            f32x4 acc = {0.f, 0.f, 0.f, 0.f};
            __builtin_amdgcn_s_setprio(1);
            acc = MFMA16(a0[s], b0, acc);
            acc = MFMA16(a1[s], b1, acc);
            __builtin_amdgcn_s_setprio(0);
            #pragma unroll
            for (int r = 0; r < 4; ++r) {
                const float u = __builtin_amdgcn_exp2f(acc[r]);
                run_s[s][r] += u;
                cs += u;
            }
        }
        cs += __shfl_xor(cs, 16, 64);
        cs += __shfl_xor(cs, 32, 64);
        if (quad == 0) cwl[wave * 128 + g * 16 + col] = cs;
    }
    __syncthreads();
    if (ti != tj && tid < 128) {
        const float c = cwl[tid] + cwl[128 + tid] + cwl[256 + tid] + cwl[384 + tid];
        part_rs[((size_t)(ti * 8 + b) << 12) + tj * 128 + tid] = c;
    }

    #pragma unroll
    for (int s = 0; s < 2; ++s)
        #pragma unroll
        for (int r = 0; r < 4; ++r) {
            #pragma unroll
            for (int off = 1; off < 16; off <<= 1)
                run_s[s][r] += __shfl_xor(run_s[s][r], off, 64);
        }
    if (col == 0) {
        #pragma unroll
        for (int s = 0; s < 2; ++s)
            #pragma unroll
            for (int r = 0; r < 4; ++r)
                part_rs[((size_t)(tj * 8 + b) << 12) + n_base + s * 16 + quad * 4 + r]
                    = run_s[s][r];
    }
}

// ---------------------------------------------------------------------------
// K2w: lw[b][n] = -log2( sum_{t<32} part_rs[t][b][n] ).  Grid 128 x 256.
// ---------------------------------------------------------------------------
__global__ __launch_bounds__(256) void k2w(
    const float* __restrict__ part_rs, float* __restrict__ lw)
{
    const int idx = blockIdx.x * 256 + threadIdx.x;    // [0, 32768)
    const int b = idx >> 12, n = idx & 4095;
    float s = 0.f;
    #pragma unroll
    for (int t = 0; t < 32; ++t)
        s += part_rs[((size_t)(t * 8 + b) << 12) + n];
    lw[b * N_ + n] = -__log2f(s);
}

// ---------------------------------------------------------------------------
// K3: R7 structure + lw via MFMA C-operand (prefetched one chunk ahead).
//     S'' = exp2(E+lw); PV uses raw xv; colsum A = ones.  DMA dbuf staging,
//     1 barrier/chunk, wave-private stS stride 40 shorts = 80 B.
//     R13 LESSON: stride 42 (84 B) broke 16-B alignment of the b128 sB reads
//     and uint2 S' writes -> compiler scalarized to b32 (conflicts 0 but 2.4x
//     slower + DVFS drag on the whole graph).  Stride MUST stay 16B-aligned;
//     the stride-40 2-way bank alias is the free kind.
//     8 waves, 32-m/wave, split-K=2, grid 512 = 2 blk/CU, 16 waves/CU.
//     launch_bounds(512,4): cap 128 >> natural ~110 -> no spill.
// ---------------------------------------------------------------------------
__global__ __launch_bounds__(512, 4) void k3_pv(
    const unsigned short* __restrict__ qk_t, const unsigned short* __restrict__ xv_bf,
    const float* __restrict__ lw,
    unsigned short* __restrict__ yb0, unsigned short* __restrict__ yb1,
    float* __restrict__ cspart)
{
    // 0..16K: qk dbuf | 16K..32K: xv dbuf | 32K..52K: stS (8 waves x 2560 B)
    __shared__ __align__(16) unsigned char lds_raw[32768 + 8 * 2560];
    const int tid = threadIdx.x;
    const int wave = tid >> 6, lane = tid & 63;
    const int quad = lane >> 4, col = lane & 15;
    const int nh2 = wave & 1, mh = wave >> 1;        // mh 0..3
    const int b = blockIdx.x & 7;
    const int m_blk = ((blockIdx.x >> 3) & 31) * 128;
    const int sk = blockIdx.x >> 8;                  // 0..1 (split-K index)
    const int n_start = sk * 2048;
    const int n_chunks = 32;
    const int m_wave = m_blk + mh * 32;
    const unsigned short* qb = qk_t + (size_t)b * N_ * C2_;
    const unsigned short* vb = xv_bf + (size_t)b * C2_ * N_;
    const float* ln = lw + b * N_;
    unsigned short* yp = (sk == 0) ? yb0 : yb1;

    // persistent B-operands for E: this wave's 32 m-cols (2 groups of 16)
    bf16x8 kb0[2], kb1[2];
    #pragma unroll
    for (int g = 0; g < 2; ++g) {
        const unsigned short* p = qb + (size_t)(m_wave + g * 16 + col) * C2_ + quad * 8;
        kb0[g] = *(const bf16x8*)p;
        kb1[g] = *(const bf16x8*)(p + 32);
    }

    // colsum A-operand: constant ones (S'' already carries the row scale)
    bf16x8 ones;
    #pragma unroll
    for (int j = 0; j < 8; ++j) ones[j] = (__bf16)1.0f;

    unsigned short* stS = (unsigned short*)(lds_raw + 32768 + wave * 2560); // [g][col][40]

    // stage one 64n qk slab + 64ch xv tile (8 KB each): 1 DMA/lane/array
    auto stage = [&](int n0, int p) {
        unsigned char* qbase = lds_raw + p * 8192;
        unsigned char* vbase = lds_raw + 16384 + p * 8192;
        const int row = tid >> 3, seg = tid & 7;
        const int ss = seg ^ (row & 7);
        gl_lds16(qb + (size_t)(n0 + row) * C2_ + (size_t)ss * 8, qbase + tid * 16);
        gl_lds16(vb + (size_t)row * N_ + n0 + ss * 8, vbase + tid * 16);
    };

    f32x4 accY[2][4];   // [g][os]
    #pragma unroll
    for (int g = 0; g < 2; ++g)
        #pragma unroll
        for (int os = 0; os < 4; ++os) accY[g][os] = (f32x4){0.f, 0.f, 0.f, 0.f};
    f32x4 csacc[2];
    #pragma unroll
    for (int g = 0; g < 2; ++g) csacc[g] = (f32x4){0.f, 0.f, 0.f, 0.f};

    // lw prefetch: this wave's 8 lw values per chunk (ns=0/1), one chunk ahead
    const float* lwp = ln + n_start + nh2 * 32 + quad * 4;
    float4 lwA = *(const float4*)(lwp);         // chunk 0, ns=0
    float4 lwB = *(const float4*)(lwp + 16);    // chunk 0, ns=1

    stage(n_start, 0);
    __syncthreads();

    for (int c = 0; c < n_chunks; ++c) {
        const int n0 = n_start + c * 64;
        const int p = c & 1;
        if (c + 1 < n_chunks) stage(n0 + 64, 1 - p);

        const unsigned short* qt = (const unsigned short*)(lds_raw + p * 8192);
        const unsigned short* vt = (const unsigned short*)(lds_raw + 16384 + p * 8192);

        // E phase; S'' = exp2(E + lw[n]) -> LDS (lw enters as MFMA C-init,
        // prefetched last chunk -> off the serial chain)
        #pragma unroll
        for (int ns = 0; ns < 2; ++ns) {
            const int row = nh2 * 32 + ns * 16 + col;
            const bf16x8 qa0 = *(const bf16x8*)(qt + row * 64 + ((quad ^ (col & 7)) * 8));
            const bf16x8 qa1 = *(const bf16x8*)(qt + row * 64 + (((4 + quad) ^ (col & 7)) * 8));
            const float4 lw4 = ns ? lwB : lwA;
            #pragma unroll
            for (int g = 0; g < 2; ++g) {
                f32x4 acc = {lw4.x, lw4.y, lw4.z, lw4.w};
                acc = MFMA16(qa0, kb0[g], acc);
                acc = MFMA16(qa1, kb1[g], acc);
                union { unsigned short us[4]; uint2 u2; } pk;
                #pragma unroll
                for (int r = 0; r < 4; ++r)
                    pk.us[r] = f2bf(__builtin_amdgcn_exp2f(acc[r]));
                *(uint2*)&stS[(g * 16 + col) * 40 + ns * 16 + quad * 4] = pk.u2;
            }
        }

        // prefetch lw for next chunk (covered by PV below)
        if (c + 1 < n_chunks) {
            lwA = *(const float4*)(lwp + (c + 1) * 64);
            lwB = *(const float4*)(lwp + (c + 1) * 64 + 16);
        }

        // same-wave round-trip: S'' as B-operand (K = this wave's 32 n)
        bf16x8 sB[2];
        #pragma unroll
        for (int g = 0; g < 2; ++g)
            sB[g] = *(const bf16x8*)&stS[(g * 16 + col) * 40 + quad * 8];

        // colsum via MFMA with A = ones -> D rows all = colsum of S''
        #pragma unroll
        for (int g = 0; g < 2; ++g)
            csacc[g] = MFMA16(ones, sB[g], csacc[g]);

        // PV: A = raw xv rows (o), k = this wave's 32 n
        #pragma unroll
        for (int os = 0; os < 4; ++os) {
            const bf16x8 va = *(const bf16x8*)(vt + (os * 16 + col) * 64 +
                                               (((nh2 * 4 + quad) ^ (col & 7)) * 8));
            #pragma unroll
            for (int g = 0; g < 2; ++g)
                accY[g][os] = MFMA16(va, sB[g], accY[g][os]);
        }
        __syncthreads();
    }

    // epilogue: combine the two n-halves (waves nh2=1 -> LDS; nh2=0 adds+writes)
    float* cmb = (float*)lds_raw;              // 32 KB: [mh][g*4+os][r][lane]
    float* csc = (float*)(lds_raw + 32768);    // 2 KB:  [mh][g][lane]
    if (nh2 == 1) {
        #pragma unroll
        for (int g = 0; g < 2; ++g) {
            #pragma unroll
            for (int os = 0; os < 4; ++os)
                #pragma unroll
                for (int r = 0; r < 4; ++r)
                    cmb[((mh * 8 + g * 4 + os) * 4 + r) * 64 + lane] = accY[g][os][r];
            csc[(mh * 2 + g) * 64 + lane] = csacc[g][0];
        }
    }
    __syncthreads();
    if (nh2 == 0) {
        #pragma unroll
        for (int g = 0; g < 2; ++g) {
            const float cs = csacc[g][0] + csc[(mh * 2 + g) * 64 + lane];
            if (lane < 16)
                cspart[((size_t)sk * 8 + b) * N_ + m_wave + g * 16 + lane] = cs;
            #pragma unroll
            for (int os = 0; os < 4; ++os)
                #pragma unroll
                for (int r = 0; r < 4; ++r) {
                    const float v = accY[g][os][r] +
                        cmb[((mh * 8 + g * 4 + os) * 4 + r) * 64 + lane];
                    yp[(size_t)(b * C2_ + os * 16 + quad * 4 + r) * N_ + m_wave + g * 16 + col]
                        = f2bf(v);
                }
        }
    }
}

// ---------------------------------------------------------------------------
// K4: fused partial-combine + w_t GEMM (MFMA) + BN stats via GLOBAL ATOMICS
//     (replaces part_bn + k5r; bn zeroed by k0, stream-ordered).
//     Grid (64, 8).  cinv = 1/(eps+sum cspart); d = xc - (y0+y1)*cinv
//     staged TRANSPOSED to LDS bf16 d_t[n][72]; w_t [o][72].  Wave = o-tile;
//     K=64.  t -> t_bf (BF16; stats from unrounded f32).
// ---------------------------------------------------------------------------
__global__ __launch_bounds__(256) void k4_t(
    const unsigned short* __restrict__ xc_bf, const unsigned short* __restrict__ y0,
    const unsigned short* __restrict__ y1,
    const float* __restrict__ cspart, const float* __restrict__ w_t,
    const float* __restrict__ b_t, unsigned short* __restrict__ t_bf,
    float* __restrict__ bn)
{
    __shared__ __align__(16) unsigned short wlds[64 * 72];
    __shared__ __align__(16) unsigned short d_t[64 * 72];
    __shared__ float cinv[64];
    const int tid = threadIdx.x;
    const int wave = tid >> 6, lane = tid & 63;
    const int quad = lane >> 4, col = lane & 15;
    const int b = blockIdx.y;
    const int n0 = blockIdx.x * 64;
    const size_t base = (size_t)b * C2_ * N_;

    #pragma unroll
    for (int it = 0; it < 4; ++it) {
        const int idx4 = it * 256 + tid;               // [0, 1024)
        const int o = idx4 >> 4, i4 = (idx4 & 15) * 4;
        const float4 v = *(const float4*)(w_t + o * 64 + i4);
        us4 pk;
        pk.a = f2bf(v.x); pk.b = f2bf(v.y); pk.c = f2bf(v.z); pk.d = f2bf(v.w);
        *(us4*)&wlds[o * 72 + i4] = pk;
    }
    if (tid < 64) {
        const int n = n0 + tid;
        const float cs = cspart[(size_t)b * N_ + n] + cspart[(size_t)(8 + b) * N_ + n];
        cinv[tid] = 1.0f / (1e-9f + cs);
    }
    __syncthreads();

    #pragma unroll
    for (int it = 0; it < 4; ++it) {
        const int idx4 = it * 256 + tid;               // [0, 1024)
        const int i = idx4 >> 4, n4 = (idx4 & 15) * 4;
        const size_t g = base + (size_t)i * N_ + n0 + n4;
        const us4 cx = *(const us4*)(xc_bf + g);
        const us4 u0 = *(const us4*)(y0 + g);
        const us4 u1 = *(const us4*)(y1 + g);
        d_t[(n4 + 0) * 72 + i] = f2bf(bf2f(cx.a) - (bf2f(u0.a) + bf2f(u1.a)) * cinv[n4 + 0]);
        d_t[(n4 + 1) * 72 + i] = f2bf(bf2f(cx.b) - (bf2f(u0.b) + bf2f(u1.b)) * cinv[n4 + 1]);
        d_t[(n4 + 2) * 72 + i] = f2bf(bf2f(cx.c) - (bf2f(u0.c) + bf2f(u1.c)) * cinv[n4 + 2]);
        d_t[(n4 + 3) * 72 + i] = f2bf(bf2f(cx.d) - (bf2f(u0.d) + bf2f(u1.d)) * cinv[n4 + 3]);
    }
    __syncthreads();

    const int ow = wave * 16;
    bf16x8 afr[2];
    #pragma unroll
    for (int kt = 0; kt < 2; ++kt)
        afr[kt] = *(const bf16x8*)&wlds[(ow + col) * 72 + kt * 32 + quad * 8];
    const float4 bt4 = *(const float4*)(b_t + ow + quad * 4);
    const float* btp = (const float*)&bt4;

    float s[4] = {0.f, 0.f, 0.f, 0.f}, q2[4] = {0.f, 0.f, 0.f, 0.f};
    #pragma unroll
    for (int ns = 0; ns < 4; ++ns) {
        f32x4 acc = {0.f, 0.f, 0.f, 0.f};
        #pragma unroll
        for (int kt = 0; kt < 2; ++kt) {
            const bf16x8 bfr = *(const bf16x8*)&d_t[(ns * 16 + col) * 72 + kt * 32 + quad * 8];
            acc = MFMA16(afr[kt], bfr, acc);
        }
        #pragma unroll
        for (int r = 0; r < 4; ++r) {
            const float t = acc[r] + btp[r];
            t_bf[base + (size_t)(ow + quad * 4 + r) * N_ + n0 + ns * 16 + col] = f2bf(t);
            s[r] += t;
            q2[r] += t * t;
        }
    }
    #pragma unroll
    for (int r = 0; r < 4; ++r) {
        #pragma unroll
        for (int off = 1; off < 16; off <<= 1) {
            s[r]  += __shfl_xor(s[r],  off, 64);
            q2[r] += __shfl_xor(q2[r], off, 64);
        }
    }
    if (col == 0) {
        #pragma unroll
        for (int r = 0; r < 4; ++r) {
            atomicAdd(&bn[ow + quad * 4 + r], s[r]);
            atomicAdd(&bn[64 + ow + quad * 4 + r], q2[r]);
        }
    }
}

// ---------------------------------------------------------------------------
// K6: out = xc + relu(gamma * (t - mean) * rsqrt(var + eps) + beta)
//     xc, t read as BF16 (us4); out written f32.
// ---------------------------------------------------------------------------
__global__ __launch_bounds__(256) void k6_out(
    const unsigned short* __restrict__ xc_bf, const unsigned short* __restrict__ t_bf,
    const float* __restrict__ bn, const float* __restrict__ gamma,
    const float* __restrict__ beta, float* __restrict__ out)
{
    const int idx = blockIdx.x * 256 + threadIdx.x;
    const int o = (idx >> 10) & 63;
    const float invC = 1.0f / (float)(B_ * N_);
    const float mean = bn[o] * invC;
    const float var  = bn[64 + o] * invC - mean * mean;
    const float sc = gamma[o] * rsqrtf(var + 1e-5f);
    const float sh = beta[o] - mean * sc;
    const us4 t4 = ((const us4*)t_bf)[idx];
    const us4 c4 = ((const us4*)xc_bf)[idx];
    float4 r;
    r.x = bf2f(c4.a) + fmaxf(0.f, sc * bf2f(t4.a) + sh);
    r.y = bf2f(c4.b) + fmaxf(0.f, sc * bf2f(t4.b) + sh);
    r.z = bf2f(c4.c) + fmaxf(0.f, sc * bf2f(t4.c) + sh);
    r.w = bf2f(c4.d) + fmaxf(0.f, sc * bf2f(t4.d) + sh);
    ((float4*)out)[idx] = r;
}

extern "C" void kernel_launch(void* const* d_in, const int* in_sizes, int n_in,
                              void* d_out, int out_size, void* d_ws, size_t ws_size,
                              hipStream_t stream) {
    const float* x     = (const float*)d_in[0];
    const float* w_qk  = (const float*)d_in[1];
    const float* w_v   = (const float*)d_in[2];
    const float* b_v   = (const float*)d_in[3];
    const float* w_x   = (const float*)d_in[4];
    const float* w_t   = (const float*)d_in[5];
    const float* b_t   = (const float*)d_in[6];
    const float* gamma = (const float*)d_in[7];
    const float* beta  = (const float*)d_in[8];
    float* out = (float*)d_out;

    char* ws = (char*)d_ws;
    unsigned short* qk_t  = (unsigned short*)ws;                      // 4 MB
    unsigned short* xv_bf = (unsigned short*)(ws + (4  << 20));       // 4 MB
    unsigned short* xc_bf = (unsigned short*)(ws + (8  << 20));       // 4 MB (bf16)
    unsigned short* t_bf  = (unsigned short*)(ws + (12 << 20));       // 4 MB (bf16)
    unsigned short* yb0 = (unsigned short*)(ws + (16 << 20));         // 4 MB (bf16 partial Y)
    unsigned short* yb1 = (unsigned short*)(ws + (20 << 20));         // 4 MB (bf16 partial Y)
    float* part_rs = (float*)(ws + (24 << 20));                       // 4 MB (k2_sym -> k2w)
    float* cspart  = (float*)(ws + (32 << 20));                       // 256 KB (k3 -> k4)
    float* bn      = (float*)(ws + (33 << 20));                       // 512 B (k4 atomics)
    // d_out doubles as scratch until k6 (k6 is the only writer of out):
    unsigned short* wstack = (unsigned short*)d_out;                  // 48 KB (k0 -> k1)
    float* lw = (float*)((char*)d_out + (256 << 10));                 // 128 KB (k2w -> k3)

    hipLaunchKernelGGL(k0_wcvt,     dim3(24),     256, 0, stream, w_qk, w_v, w_x, wstack, bn);
    hipLaunchKernelGGL(k1_proj,     dim3(64, 8),  256, 0, stream,
                       x, wstack, b_v, qk_t, xv_bf, xc_bf);
    hipLaunchKernelGGL(k2_sym,      dim3(4224),   256, 0, stream, qk_t, part_rs);
    hipLaunchKernelGGL(k2w,         dim3(128),    256, 0, stream, part_rs, lw);
    hipLaunchKernelGGL(k3_pv,       dim3(512),    512, 0, stream,
                       qk_t, xv_bf, lw, yb0, yb1, cspart);
    hipLaunchKernelGGL(k4_t,        dim3(64, 8),  256, 0, stream,
                       xc_bf, yb0, yb1, cspart, w_t, b_t, t_bf, bn);
    hipLaunchKernelGGL(k6_out,      dim3(2048),   256, 0, stream, xc_bf, t_bf, bn, gamma, beta, out);
}

// Round 15
// 165.773 us; speedup vs baseline: 1.7037x; 1.2770x over previous
//
#include <hip/hip_runtime.h>

#define B_   8
#define C_   128
#define N_   4096
#define C2_  64

typedef __bf16 bf16x8 __attribute__((ext_vector_type(8)));
typedef float  f32x4  __attribute__((ext_vector_type(4)));

#define MFMA16(a, b, c) __builtin_amdgcn_mfma_f32_16x16x32_bf16((a), (b), (c), 0, 0, 0)

// sqrt(log2(e)): folded into w_qk by k0 so softmax uses exp2 directly
#define QK_SCALE 1.2011224087864498f

static __device__ __forceinline__ unsigned short f2bf(float f) {
    union { __bf16 b; unsigned short u; } cv;
    cv.b = (__bf16)f;
    return cv.u;
}
static __device__ __forceinline__ float bf2f(unsigned short u) {
    union { unsigned int u; float f; } cv;
    cv.u = ((unsigned int)u) << 16;
    return cv.f;
}

struct us4 { unsigned short a, b, c, d; };

// async global->LDS, 16 B per lane.  LDS dest must be linear in lane order.
static __device__ __forceinline__ void gl_lds16(const unsigned short* g, void* l) {
    __builtin_amdgcn_global_load_lds(
        (const __attribute__((address_space(1))) unsigned int*)g,
        (__attribute__((address_space(3))) unsigned int*)l,
        16, 0, 0);
}

// ---------------------------------------------------------------------------
// K0: one-time weight convert f32 -> bf16, stacked [w_qk; w_v; w_x] = [192][128].
//     QK_SCALE folded into w_qk rows.  24576 elems, grid 24 x 256 x 4.
// ---------------------------------------------------------------------------
__global__ __launch_bounds__(256) void k0_wcvt(
    const float* __restrict__ wq, const float* __restrict__ wv,
    const float* __restrict__ wx, unsigned short* __restrict__ wst)
{
    const int i4 = (blockIdx.x * 256 + threadIdx.x) * 4;   // [0, 24576)
    const int mat = i4 >> 13;                              // 8192 elems / matrix
    const float* src = (mat == 0) ? wq : (mat == 1) ? wv : wx;
    const float sc = (mat == 0) ? QK_SCALE : 1.0f;
    const float4 v = *(const float4*)(src + (i4 & 8191));
    us4 pk;
    pk.a = f2bf(v.x * sc); pk.b = f2bf(v.y * sc);
    pk.c = f2bf(v.z * sc); pk.d = f2bf(v.w * sc);
    *(us4*)(wst + i4) = pk;
}

// ---------------------------------------------------------------------------
// K1: fused projection GEMM.  D[192 o][64 n] = Wst[o][c] * x[c][n] per
//     (b, 64-n tile).  Weights (bf16 from k0) DMA-staged XOR-swizzled ->
//     LDS [192][128]; x tile transposed -> LDS bf16 x_t[64 n][136 c].
//     Epilogue: ot 0-3 -> qk_t; ot 4-7 -> xv_bf (+b_v); ot 8-11 -> xc (BF16).
// ---------------------------------------------------------------------------
__global__ __launch_bounds__(256) void k1_proj(
    const float* __restrict__ x, const unsigned short* __restrict__ wst,
    const float* __restrict__ b_v,
    unsigned short* __restrict__ qk_t, unsigned short* __restrict__ xv_bf,
    unsigned short* __restrict__ xc_bf)
{
    __shared__ __align__(16) unsigned short w_lds[192 * 128];
    __shared__ __align__(16) unsigned short x_t[64 * 136];
    const int tid = threadIdx.x;
    const int wave = tid >> 6, lane = tid & 63;
    const int quad = lane >> 4, col = lane & 15;
    const int b = blockIdx.y;
    const int n0 = blockIdx.x * 64;

    #pragma unroll
    for (int it = 0; it < 12; ++it) {
        const int idx = it * 256 + tid;                // [0, 3072)
        const int row = idx >> 4, seg = idx & 15;
        gl_lds16(wst + (size_t)row * 128 + (size_t)(seg ^ (row & 7)) * 8,
                 w_lds + idx * 8);
    }
    const float* xb = x + (size_t)b * C_ * N_ + n0;
    #pragma unroll
    for (int it = 0; it < 8; ++it) {
        const int idx = it * 256 + tid;                // [0, 2048)
        const int c = idx >> 4, n = (idx & 15) * 4;
        const float4 v = *(const float4*)(xb + (size_t)c * N_ + n);
        x_t[(n + 0) * 136 + c] = f2bf(v.x);
        x_t[(n + 1) * 136 + c] = f2bf(v.y);
        x_t[(n + 2) * 136 + c] = f2bf(v.z);
        x_t[(n + 3) * 136 + c] = f2bf(v.w);
    }
    __syncthreads();

    const int nw = wave * 16;
    bf16x8 bfr[4];
    #pragma unroll
    for (int kt = 0; kt < 4; ++kt)
        bfr[kt] = *(const bf16x8*)&x_t[(nw + col) * 136 + kt * 32 + quad * 8];

    const int n_g = n0 + nw + col;

    #pragma unroll
    for (int ot = 0; ot < 12; ++ot) {
        f32x4 acc = {0.f, 0.f, 0.f, 0.f};
        #pragma unroll
        for (int kt = 0; kt < 4; ++kt) {
            const bf16x8 afr = *(const bf16x8*)&w_lds[
                ((ot * 16 + col) << 7) + (((kt * 4 + quad) ^ (col & 7)) << 3)];
            acc = MFMA16(afr, bfr[kt], acc);
        }
        if (ot < 4) {
            us4 pk;
            pk.a = f2bf(acc[0]); pk.b = f2bf(acc[1]);
            pk.c = f2bf(acc[2]); pk.d = f2bf(acc[3]);
            *(us4*)&qk_t[(size_t)(b * N_ + n_g) * C2_ + ot * 16 + quad * 4] = pk;
        } else if (ot < 8) {
            const float4 bv4 = *(const float4*)(b_v + (ot - 4) * 16 + quad * 4);
            const float* bvp = (const float*)&bv4;
            #pragma unroll
            for (int r = 0; r < 4; ++r)
                xv_bf[(size_t)(b * C2_ + (ot - 4) * 16 + quad * 4 + r) * N_ + n_g]
                    = f2bf(acc[r] + bvp[r]);
        } else {
            #pragma unroll
            for (int r = 0; r < 4; ++r)
                xc_bf[(size_t)(b * C2_ + (ot - 8) * 16 + quad * 4 + r) * N_ + n_g]
                    = f2bf(acc[r]);
        }
    }
}

// ---------------------------------------------------------------------------
// K2_sym: partial row softmax sums exploiting E symmetry (E[n][m]=E[m][n]
//     since q,k share w_qk).  Only tiles ti<=tj computed: 528/1024 = 51.6%
//     of E-GEMM+exp2.  Off-diag tile (ti,tj): row sums -> range ti slot tj,
//     col sums -> range tj slot ti; diag: rows only.  Every (slot,range)
//     written once -> no atomics.  part_rs[32][8][4096].  Grid 4224.
// ---------------------------------------------------------------------------
__global__ __launch_bounds__(256) void k2_sym(
    const unsigned short* __restrict__ qk_t, float* __restrict__ part_rs)
{
    __shared__ __align__(16) unsigned short slab[128 * 64];
    __shared__ float cwl[4 * 128];
    const int tid = threadIdx.x;
    const int wave = tid >> 6, lane = tid & 63;
    const int quad = lane >> 4, col = lane & 15;
    const int b = blockIdx.x & 7;
    int job = blockIdx.x >> 3, ti = 0;                 // job in [0,528)
    while (job >= 32 - ti) { job -= 32 - ti; ++ti; }
    const int tj = ti + job;
    const unsigned short* qb = qk_t + (size_t)b * N_ * C2_;

    const int n_base = ti * 128 + wave * 32;
    bf16x8 a0[2], a1[2];
    #pragma unroll
    for (int s = 0; s < 2; ++s) {
        const unsigned short* p = qb + (size_t)(n_base + s * 16 + col) * C2_ + quad * 8;
        a0[s] = *(const bf16x8*)p;
        a1[s] = *(const bf16x8*)(p + 32);
    }

    #pragma unroll
    for (int r = 0; r < 4; ++r) {
        const int idx = r * 256 + tid;                 // [0, 1024)
        const int row = idx >> 3, seg = idx & 7;
        gl_lds16(qb + (size_t)(tj * 128 + row) * C2_ + (size_t)(seg ^ (row & 7)) * 8,
                 slab + idx * 8);
    }
    __syncthreads();

    float run_s[2][4];
    #pragma unroll
    for (int s = 0; s < 2; ++s)
        #pragma unroll
        for (int r = 0; r < 4; ++r) run_s[s][r] = 0.f;

    #pragma unroll
    for (int g = 0; g < 8; ++g) {
        const int row = g * 16 + col;
        const bf16x8 b0 = *(const bf16x8*)(slab + row * 64 + ((quad ^ (col & 7)) * 8));
        const bf16x8 b1 = *(const bf16x8*)(slab + row * 64 + (((4 + quad) ^ (col & 7)) * 8));
        float cs = 0.f;
        #pragma unroll
        for (int s = 0; s < 2; ++s) {
            f32x4 acc = {0.f, 0.f, 0.f, 0.f};
            __builtin_amdgcn_s_setprio(1);
            acc = MFMA16(a0[s], b0, acc);
            acc = MFMA16(a1[s], b1, acc);
            __builtin_amdgcn_s_setprio(0);
            #pragma unroll
            for (int r = 0; r < 4; ++r) {
                const float u = __builtin_amdgcn_exp2f(acc[r]);
                run_s[s][r] += u;
                cs += u;
            }
        }
        cs += __shfl_xor(cs, 16, 64);
        cs += __shfl_xor(cs, 32, 64);
        if (quad == 0) cwl[wave * 128 + g * 16 + col] = cs;
    }
    __syncthreads();
    if (ti != tj && tid < 128) {
        const float c = cwl[tid] + cwl[128 + tid] + cwl[256 + tid] + cwl[384 + tid];
        part_rs[((size_t)(ti * 8 + b) << 12) + tj * 128 + tid] = c;
    }

    #pragma unroll
    for (int s = 0; s < 2; ++s)
        #pragma unroll
        for (int r = 0; r < 4; ++r) {
            #pragma unroll
            for (int off = 1; off < 16; off <<= 1)
                run_s[s][r] += __shfl_xor(run_s[s][r], off, 64);
        }
    if (col == 0) {
        #pragma unroll
        for (int s = 0; s < 2; ++s)
            #pragma unroll
            for (int r = 0; r < 4; ++r)
                part_rs[((size_t)(tj * 8 + b) << 12) + n_base + s * 16 + quad * 4 + r]
                    = run_s[s][r];
    }
}

// ---------------------------------------------------------------------------
// K2w: lw[b][n] = -log2( sum_{t<32} part_rs[t][b][n] ).  Grid 128 x 256.
// ---------------------------------------------------------------------------
__global__ __launch_bounds__(256) void k2w(
    const float* __restrict__ part_rs, float* __restrict__ lw)
{
    const int idx = blockIdx.x * 256 + threadIdx.x;    // [0, 32768)
    const int b = idx >> 12, n = idx & 4095;
    float s = 0.f;
    #pragma unroll
    for (int t = 0; t < 32; ++t)
        s += part_rs[((size_t)(t * 8 + b) << 12) + n];
    lw[b * N_ + n] = -__log2f(s);
}

// ---------------------------------------------------------------------------
// K3: R7 structure + lw via MFMA C-operand (prefetched one chunk ahead;
//     R11: at-use lw loads sit in the E serial chain).  S'' = exp2(E+lw);
//     PV uses raw xv; colsum A = ones.  DMA dbuf staging, 1 barrier/chunk,
//     wave-private stS stride 40 shorts = 80 B (16B-ALIGNED -- R13: stride
//     42 broke b128 alignment, scalarized LDS ops, 2.4x slower).
//     8 waves, 32-m/wave, split-K=2, grid 512 = 2 blk/CU, 16 waves/CU.
//     launch_bounds(512,4): cap 128 >> natural ~110 -> no spill.
// ---------------------------------------------------------------------------
__global__ __launch_bounds__(512, 4) void k3_pv(
    const unsigned short* __restrict__ qk_t, const unsigned short* __restrict__ xv_bf,
    const float* __restrict__ lw,
    unsigned short* __restrict__ yb0, unsigned short* __restrict__ yb1,
    float* __restrict__ cspart)
{
    // 0..16K: qk dbuf | 16K..32K: xv dbuf | 32K..52K: stS (8 waves x 2560 B)
    __shared__ __align__(16) unsigned char lds_raw[32768 + 8 * 2560];
    const int tid = threadIdx.x;
    const int wave = tid >> 6, lane = tid & 63;
    const int quad = lane >> 4, col = lane & 15;
    const int nh2 = wave & 1, mh = wave >> 1;        // mh 0..3
    const int b = blockIdx.x & 7;
    const int m_blk = ((blockIdx.x >> 3) & 31) * 128;
    const int sk = blockIdx.x >> 8;                  // 0..1 (split-K index)
    const int n_start = sk * 2048;
    const int n_chunks = 32;
    const int m_wave = m_blk + mh * 32;
    const unsigned short* qb = qk_t + (size_t)b * N_ * C2_;
    const unsigned short* vb = xv_bf + (size_t)b * C2_ * N_;
    const float* ln = lw + b * N_;
    unsigned short* yp = (sk == 0) ? yb0 : yb1;

    // persistent B-operands for E: this wave's 32 m-cols (2 groups of 16)
    bf16x8 kb0[2], kb1[2];
    #pragma unroll
    for (int g = 0; g < 2; ++g) {
        const unsigned short* p = qb + (size_t)(m_wave + g * 16 + col) * C2_ + quad * 8;
        kb0[g] = *(const bf16x8*)p;
        kb1[g] = *(const bf16x8*)(p + 32);
    }

    // colsum A-operand: constant ones (S'' already carries the row scale)
    bf16x8 ones;
    #pragma unroll
    for (int j = 0; j < 8; ++j) ones[j] = (__bf16)1.0f;

    unsigned short* stS = (unsigned short*)(lds_raw + 32768 + wave * 2560); // [g][col][40]

    // stage one 64n qk slab + 64ch xv tile (8 KB each): 1 DMA/lane/array
    auto stage = [&](int n0, int p) {
        unsigned char* qbase = lds_raw + p * 8192;
        unsigned char* vbase = lds_raw + 16384 + p * 8192;
        const int row = tid >> 3, seg = tid & 7;
        const int ss = seg ^ (row & 7);
        gl_lds16(qb + (size_t)(n0 + row) * C2_ + (size_t)ss * 8, qbase + tid * 16);
        gl_lds16(vb + (size_t)row * N_ + n0 + ss * 8, vbase + tid * 16);
    };

    f32x4 accY[2][4];   // [g][os]
    #pragma unroll
    for (int g = 0; g < 2; ++g)
        #pragma unroll
        for (int os = 0; os < 4; ++os) accY[g][os] = (f32x4){0.f, 0.f, 0.f, 0.f};
    f32x4 csacc[2];
    #pragma unroll
    for (int g = 0; g < 2; ++g) csacc[g] = (f32x4){0.f, 0.f, 0.f, 0.f};

    // lw prefetch: this wave's 8 lw values per chunk (ns=0/1), one chunk ahead
    const float* lwp = ln + n_start + nh2 * 32 + quad * 4;
    float4 lwA = *(const float4*)(lwp);         // chunk 0, ns=0
    float4 lwB = *(const float4*)(lwp + 16);    // chunk 0, ns=1

    stage(n_start, 0);
    __syncthreads();

    for (int c = 0; c < n_chunks; ++c) {
        const int n0 = n_start + c * 64;
        const int p = c & 1;
        if (c + 1 < n_chunks) stage(n0 + 64, 1 - p);

        const unsigned short* qt = (const unsigned short*)(lds_raw + p * 8192);
        const unsigned short* vt = (const unsigned short*)(lds_raw + 16384 + p * 8192);

        // E phase; S'' = exp2(E + lw[n]) -> LDS (lw enters as MFMA C-init,
        // prefetched last chunk -> off the serial chain)
        #pragma unroll
        for (int ns = 0; ns < 2; ++ns) {
            const int row = nh2 * 32 + ns * 16 + col;
            const bf16x8 qa0 = *(const bf16x8*)(qt + row * 64 + ((quad ^ (col & 7)) * 8));
            const bf16x8 qa1 = *(const bf16x8*)(qt + row * 64 + (((4 + quad) ^ (col & 7)) * 8));
            const float4 lw4 = ns ? lwB : lwA;
            #pragma unroll
            for (int g = 0; g < 2; ++g) {
                f32x4 acc = {lw4.x, lw4.y, lw4.z, lw4.w};
                acc = MFMA16(qa0, kb0[g], acc);
                acc = MFMA16(qa1, kb1[g], acc);
                union { unsigned short us[4]; uint2 u2; } pk;
                #pragma unroll
                for (int r = 0; r < 4; ++r)
                    pk.us[r] = f2bf(__builtin_amdgcn_exp2f(acc[r]));
                *(uint2*)&stS[(g * 16 + col) * 40 + ns * 16 + quad * 4] = pk.u2;
            }
        }

        // prefetch lw for next chunk (covered by PV below)
        if (c + 1 < n_chunks) {
            lwA = *(const float4*)(lwp + (c + 1) * 64);
            lwB = *(const float4*)(lwp + (c + 1) * 64 + 16);
        }

        // same-wave round-trip: S'' as B-operand (K = this wave's 32 n)
        bf16x8 sB[2];
        #pragma unroll
        for (int g = 0; g < 2; ++g)
            sB[g] = *(const bf16x8*)&stS[(g * 16 + col) * 40 + quad * 8];

        // colsum via MFMA with A = ones -> D rows all = colsum of S''
        #pragma unroll
        for (int g = 0; g < 2; ++g)
            csacc[g] = MFMA16(ones, sB[g], csacc[g]);

        // PV: A = raw xv rows (o), k = this wave's 32 n
        #pragma unroll
        for (int os = 0; os < 4; ++os) {
            const bf16x8 va = *(const bf16x8*)(vt + (os * 16 + col) * 64 +
                                               (((nh2 * 4 + quad) ^ (col & 7)) * 8));
            #pragma unroll
            for (int g = 0; g < 2; ++g)
                accY[g][os] = MFMA16(va, sB[g], accY[g][os]);
        }
        __syncthreads();
    }

    // epilogue: combine the two n-halves (waves nh2=1 -> LDS; nh2=0 adds+writes)
    float* cmb = (float*)lds_raw;              // 32 KB: [mh][g*4+os][r][lane]
    float* csc = (float*)(lds_raw + 32768);    // 2 KB:  [mh][g][lane]
    if (nh2 == 1) {
        #pragma unroll
        for (int g = 0; g < 2; ++g) {
            #pragma unroll
            for (int os = 0; os < 4; ++os)
                #pragma unroll
                for (int r = 0; r < 4; ++r)
                    cmb[((mh * 8 + g * 4 + os) * 4 + r) * 64 + lane] = accY[g][os][r];
            csc[(mh * 2 + g) * 64 + lane] = csacc[g][0];
        }
    }
    __syncthreads();
    if (nh2 == 0) {
        #pragma unroll
        for (int g = 0; g < 2; ++g) {
            const float cs = csacc[g][0] + csc[(mh * 2 + g) * 64 + lane];
            if (lane < 16)
                cspart[((size_t)sk * 8 + b) * N_ + m_wave + g * 16 + lane] = cs;
            #pragma unroll
            for (int os = 0; os < 4; ++os)
                #pragma unroll
                for (int r = 0; r < 4; ++r) {
                    const float v = accY[g][os][r] +
                        cmb[((mh * 8 + g * 4 + os) * 4 + r) * 64 + lane];
                    yp[(size_t)(b * C2_ + os * 16 + quad * 4 + r) * N_ + m_wave + g * 16 + col]
                        = f2bf(v);
                }
        }
    }
}

// ---------------------------------------------------------------------------
// K4: fused partial-combine + w_t GEMM (MFMA) + BN partial stats.
//     Grid (64, 8).  cinv = 1/(eps+sum cspart); d = xc - (y0+y1)*cinv
//     (xc BF16) staged TRANSPOSED to LDS bf16 d_t[n][72]; w_t [o][72].
//     Wave = o-tile; K=64.  t -> t_bf (BF16; stats from unrounded f32);
//     per-block channel partials -> part_bn[c][blk] (streaming writes --
//     R14 LESSON: 512-block atomicAdd to a 512B bn region serializes
//     cross-XCD at the fabric, +45us; never contend atomics on hot lines).
// ---------------------------------------------------------------------------
__global__ __launch_bounds__(256) void k4_t(
    const unsigned short* __restrict__ xc_bf, const unsigned short* __restrict__ y0,
    const unsigned short* __restrict__ y1,
    const float* __restrict__ cspart, const float* __restrict__ w_t,
    const float* __restrict__ b_t, unsigned short* __restrict__ t_bf,
    float* __restrict__ part_bn)
{
    __shared__ __align__(16) unsigned short wlds[64 * 72];
    __shared__ __align__(16) unsigned short d_t[64 * 72];
    __shared__ float cinv[64];
    const int tid = threadIdx.x;
    const int wave = tid >> 6, lane = tid & 63;
    const int quad = lane >> 4, col = lane & 15;
    const int b = blockIdx.y;
    const int n0 = blockIdx.x * 64;
    const size_t base = (size_t)b * C2_ * N_;

    #pragma unroll
    for (int it = 0; it < 4; ++it) {
        const int idx4 = it * 256 + tid;               // [0, 1024)
        const int o = idx4 >> 4, i4 = (idx4 & 15) * 4;
        const float4 v = *(const float4*)(w_t + o * 64 + i4);
        us4 pk;
        pk.a = f2bf(v.x); pk.b = f2bf(v.y); pk.c = f2bf(v.z); pk.d = f2bf(v.w);
        *(us4*)&wlds[o * 72 + i4] = pk;
    }
    if (tid < 64) {
        const int n = n0 + tid;
        const float cs = cspart[(size_t)b * N_ + n] + cspart[(size_t)(8 + b) * N_ + n];
        cinv[tid] = 1.0f / (1e-9f + cs);
    }
    __syncthreads();

    #pragma unroll
    for (int it = 0; it < 4; ++it) {
        const int idx4 = it * 256 + tid;               // [0, 1024)
        const int i = idx4 >> 4, n4 = (idx4 & 15) * 4;
        const size_t g = base + (size_t)i * N_ + n0 + n4;
        const us4 cx = *(const us4*)(xc_bf + g);
        const us4 u0 = *(const us4*)(y0 + g);
        const us4 u1 = *(const us4*)(y1 + g);
        d_t[(n4 + 0) * 72 + i] = f2bf(bf2f(cx.a) - (bf2f(u0.a) + bf2f(u1.a)) * cinv[n4 + 0]);
        d_t[(n4 + 1) * 72 + i] = f2bf(bf2f(cx.b) - (bf2f(u0.b) + bf2f(u1.b)) * cinv[n4 + 1]);
        d_t[(n4 + 2) * 72 + i] = f2bf(bf2f(cx.c) - (bf2f(u0.c) + bf2f(u1.c)) * cinv[n4 + 2]);
        d_t[(n4 + 3) * 72 + i] = f2bf(bf2f(cx.d) - (bf2f(u0.d) + bf2f(u1.d)) * cinv[n4 + 3]);
    }
    __syncthreads();

    const int ow = wave * 16;
    bf16x8 afr[2];
    #pragma unroll
    for (int kt = 0; kt < 2; ++kt)
        afr[kt] = *(const bf16x8*)&wlds[(ow + col) * 72 + kt * 32 + quad * 8];
    const float4 bt4 = *(const float4*)(b_t + ow + quad * 4);
    const float* btp = (const float*)&bt4;

    float s[4] = {0.f, 0.f, 0.f, 0.f}, q2[4] = {0.f, 0.f, 0.f, 0.f};
    #pragma unroll
    for (int ns = 0; ns < 4; ++ns) {
        f32x4 acc = {0.f, 0.f, 0.f, 0.f};
        #pragma unroll
        for (int kt = 0; kt < 2; ++kt) {
            const bf16x8 bfr = *(const bf16x8*)&d_t[(ns * 16 + col) * 72 + kt * 32 + quad * 8];
            acc = MFMA16(afr[kt], bfr, acc);
        }
        #pragma unroll
        for (int r = 0; r < 4; ++r) {
            const float t = acc[r] + btp[r];
            t_bf[base + (size_t)(ow + quad * 4 + r) * N_ + n0 + ns * 16 + col] = f2bf(t);
            s[r] += t;
            q2[r] += t * t;
        }
    }
    #pragma unroll
    for (int r = 0; r < 4; ++r) {
        #pragma unroll
        for (int off = 1; off < 16; off <<= 1) {
            s[r]  += __shfl_xor(s[r],  off, 64);
            q2[r] += __shfl_xor(q2[r], off, 64);
        }
    }
    if (col == 0) {
        const int blk = blockIdx.x * 8 + b;            // [0, 512)
        #pragma unroll
        for (int r = 0; r < 4; ++r) {
            part_bn[(size_t)(ow + quad * 4 + r) * 512 + blk]      = s[r];
            part_bn[(size_t)(64 + ow + quad * 4 + r) * 512 + blk] = q2[r];
        }
    }
}

// K5r: bn[c] = sum_blk part_bn[c][blk], c in [0,128)
__global__ __launch_bounds__(256) void k5r(
    const float* __restrict__ part_bn, float* __restrict__ bn)
{
    const int c = blockIdx.x;
    const int tid = threadIdx.x, wave = tid >> 6, lane = tid & 63;
    float s = 0.f;
    for (int j = tid; j < 512; j += 256) s += part_bn[(size_t)c * 512 + j];
    #pragma unroll
    for (int off = 1; off < 64; off <<= 1) s += __shfl_xor(s, off, 64);
    __shared__ float red[4];
    if (lane == 0) red[wave] = s;
    __syncthreads();
    if (tid == 0) bn[c] = red[0] + red[1] + red[2] + red[3];
}

// ---------------------------------------------------------------------------
// K6: out = xc + relu(gamma * (t - mean) * rsqrt(var + eps) + beta)
//     xc, t read as BF16 (us4); out written f32.
// ---------------------------------------------------------------------------
__global__ __launch_bounds__(256) void k6_out(
    const unsigned short* __restrict__ xc_bf, const unsigned short* __restrict__ t_bf,
    const float* __restrict__ bn, const float* __restrict__ gamma,
    const float* __restrict__ beta, float* __restrict__ out)
{
    const int idx = blockIdx.x * 256 + threadIdx.x;
    const int o = (idx >> 10) & 63;
    const float invC = 1.0f / (float)(B_ * N_);
    const float mean = bn[o] * invC;
    const float var  = bn[64 + o] * invC - mean * mean;
    const float sc = gamma[o] * rsqrtf(var + 1e-5f);
    const float sh = beta[o] - mean * sc;
    const us4 t4 = ((const us4*)t_bf)[idx];
    const us4 c4 = ((const us4*)xc_bf)[idx];
    float4 r;
    r.x = bf2f(c4.a) + fmaxf(0.f, sc * bf2f(t4.a) + sh);
    r.y = bf2f(c4.b) + fmaxf(0.f, sc * bf2f(t4.b) + sh);
    r.z = bf2f(c4.c) + fmaxf(0.f, sc * bf2f(t4.c) + sh);
    r.w = bf2f(c4.d) + fmaxf(0.f, sc * bf2f(t4.d) + sh);
    ((float4*)out)[idx] = r;
}

extern "C" void kernel_launch(void* const* d_in, const int* in_sizes, int n_in,
                              void* d_out, int out_size, void* d_ws, size_t ws_size,
                              hipStream_t stream) {
    const float* x     = (const float*)d_in[0];
    const float* w_qk  = (const float*)d_in[1];
    const float* w_v   = (const float*)d_in[2];
    const float* b_v   = (const float*)d_in[3];
    const float* w_x   = (const float*)d_in[4];
    const float* w_t   = (const float*)d_in[5];
    const float* b_t   = (const float*)d_in[6];
    const float* gamma = (const float*)d_in[7];
    const float* beta  = (const float*)d_in[8];
    float* out = (float*)d_out;

    char* ws = (char*)d_ws;
    unsigned short* qk_t  = (unsigned short*)ws;                      // 4 MB
    unsigned short* xv_bf = (unsigned short*)(ws + (4  << 20));       // 4 MB
    unsigned short* xc_bf = (unsigned short*)(ws + (8  << 20));       // 4 MB (bf16)
    unsigned short* t_bf  = (unsigned short*)(ws + (12 << 20));       // 4 MB (bf16)
    unsigned short* yb0 = (unsigned short*)(ws + (16 << 20));         // 4 MB (bf16 partial Y)
    unsigned short* yb1 = (unsigned short*)(ws + (20 << 20));         // 4 MB (bf16 partial Y)
    float* part_rs = (float*)(ws + (24 << 20));                       // 4 MB (k2_sym -> k2w)
    float* cspart  = (float*)(ws + (32 << 20));                       // 256 KB (k3 -> k4)
    float* part_bn = (float*)(ws + (33 << 20));                       // 256 KB
    float* bn      = (float*)(ws + (33 << 20) + (256 << 10));         // 512 B
    // d_out doubles as scratch until k6 (k6 is the only writer of out):
    unsigned short* wstack = (unsigned short*)d_out;                  // 48 KB (k0 -> k1)
    float* lw = (float*)((char*)d_out + (256 << 10));                 // 128 KB (k2w -> k3)

    hipLaunchKernelGGL(k0_wcvt,     dim3(24),     256, 0, stream, w_qk, w_v, w_x, wstack);
    hipLaunchKernelGGL(k1_proj,     dim3(64, 8),  256, 0, stream,
                       x, wstack, b_v, qk_t, xv_bf, xc_bf);
    hipLaunchKernelGGL(k2_sym,      dim3(4224),   256, 0, stream, qk_t, part_rs);
    hipLaunchKernelGGL(k2w,         dim3(128),    256, 0, stream, part_rs, lw);
    hipLaunchKernelGGL(k3_pv,       dim3(512),    512, 0, stream,
                       qk_t, xv_bf, lw, yb0, yb1, cspart);
    hipLaunchKernelGGL(k4_t,        dim3(64, 8),  256, 0, stream,
                       xc_bf, yb0, yb1, cspart, w_t, b_t, t_bf, part_bn);
    hipLaunchKernelGGL(k5r,         dim3(128),    256, 0, stream, part_bn, bn);
    hipLaunchKernelGGL(k6_out,      dim3(2048),   256, 0, stream, xc_bf, t_bf, bn, gamma, beta, out);
}

// Round 16
// 163.635 us; speedup vs baseline: 1.7260x; 1.0131x over previous
//
#include <hip/hip_runtime.h>

#define B_   8
#define C_   128
#define N_   4096
#define C2_  64

typedef __bf16 bf16x8 __attribute__((ext_vector_type(8)));
typedef float  f32x4  __attribute__((ext_vector_type(4)));

#define MFMA16(a, b, c) __builtin_amdgcn_mfma_f32_16x16x32_bf16((a), (b), (c), 0, 0, 0)

// sqrt(log2(e)): fold into q/k so softmax uses exp2 directly (E' = E * log2e)
#define QK_SCALE 1.2011224087864498f

static __device__ __forceinline__ unsigned short f2bf(float f) {
    union { __bf16 b; unsigned short u; } cv;
    cv.b = (__bf16)f;
    return cv.u;
}
static __device__ __forceinline__ float bf2f(unsigned short u) {
    union { unsigned int u; float f; } cv;
    cv.u = ((unsigned int)u) << 16;
    return cv.f;
}

struct us4 { unsigned short a, b, c, d; };

// async global->LDS, 16 B per lane.  LDS dest must be linear in lane order.
static __device__ __forceinline__ void gl_lds16(const unsigned short* g, void* l) {
    __builtin_amdgcn_global_load_lds(
        (const __attribute__((address_space(1))) unsigned int*)g,
        (__attribute__((address_space(3))) unsigned int*)l,
        16, 0, 0);
}

// ---------------------------------------------------------------------------
// K1: fused projection GEMM (k0 weight-convert merged back in -- R8 measured
//     the split as cost-neutral, so inlining saves a launch).
//     D[192 o][64 n] = W(3x64 stacked)[o][c] * x[c][n] per (b, 64-n tile).
//     Weights f32 -> bf16 LDS [192][136]; x transposed -> x_t[64][136].
//     Epilogue: ot 0-3 -> qk_t (*QK_SCALE); 4-7 -> xv_bf (+b_v); 8-11 -> xc bf16.
// ---------------------------------------------------------------------------
__global__ __launch_bounds__(256) void k1_proj(
    const float* __restrict__ x, const float* __restrict__ w_qk,
    const float* __restrict__ w_v, const float* __restrict__ b_v,
    const float* __restrict__ w_x,
    unsigned short* __restrict__ qk_t, unsigned short* __restrict__ xv_bf,
    unsigned short* __restrict__ xc_bf)
{
    __shared__ __align__(16) unsigned short w_lds[192 * 136];
    __shared__ __align__(16) unsigned short x_t[64 * 136];
    const int tid = threadIdx.x;
    const int wave = tid >> 6, lane = tid & 63;
    const int quad = lane >> 4, col = lane & 15;
    const int b = blockIdx.y;
    const int n0 = blockIdx.x * 64;

    const float* wsrc[3] = {w_qk, w_v, w_x};
    #pragma unroll
    for (int mat = 0; mat < 3; ++mat) {
        const float* wm = wsrc[mat];
        #pragma unroll
        for (int it = 0; it < 8; ++it) {
            const int idx = it * 256 + tid;            // [0, 2048)
            const int o = idx >> 5, c = (idx & 31) * 4;
            const float4 v = *(const float4*)(wm + o * C_ + c);
            us4 pk;
            pk.a = f2bf(v.x); pk.b = f2bf(v.y); pk.c = f2bf(v.z); pk.d = f2bf(v.w);
            *(us4*)&w_lds[(mat * 64 + o) * 136 + c] = pk;
        }
    }
    const float* xb = x + (size_t)b * C_ * N_ + n0;
    #pragma unroll
    for (int it = 0; it < 8; ++it) {
        const int idx = it * 256 + tid;                // [0, 2048)
        const int c = idx >> 4, n = (idx & 15) * 4;
        const float4 v = *(const float4*)(xb + (size_t)c * N_ + n);
        x_t[(n + 0) * 136 + c] = f2bf(v.x);
        x_t[(n + 1) * 136 + c] = f2bf(v.y);
        x_t[(n + 2) * 136 + c] = f2bf(v.z);
        x_t[(n + 3) * 136 + c] = f2bf(v.w);
    }
    __syncthreads();

    const int nw = wave * 16;
    bf16x8 bfr[4];
    #pragma unroll
    for (int kt = 0; kt < 4; ++kt)
        bfr[kt] = *(const bf16x8*)&x_t[(nw + col) * 136 + kt * 32 + quad * 8];

    const int n_g = n0 + nw + col;

    #pragma unroll
    for (int ot = 0; ot < 12; ++ot) {
        f32x4 acc = {0.f, 0.f, 0.f, 0.f};
        #pragma unroll
        for (int kt = 0; kt < 4; ++kt) {
            const bf16x8 afr = *(const bf16x8*)&w_lds[(ot * 16 + col) * 136 + kt * 32 + quad * 8];
            acc = MFMA16(afr, bfr[kt], acc);
        }
        if (ot < 4) {
            us4 pk;
            pk.a = f2bf(acc[0] * QK_SCALE); pk.b = f2bf(acc[1] * QK_SCALE);
            pk.c = f2bf(acc[2] * QK_SCALE); pk.d = f2bf(acc[3] * QK_SCALE);
            *(us4*)&qk_t[(size_t)(b * N_ + n_g) * C2_ + ot * 16 + quad * 4] = pk;
        } else if (ot < 8) {
            const float4 bv4 = *(const float4*)(b_v + (ot - 4) * 16 + quad * 4);
            const float* bvp = (const float*)&bv4;
            #pragma unroll
            for (int r = 0; r < 4; ++r)
                xv_bf[(size_t)(b * C2_ + (ot - 4) * 16 + quad * 4 + r) * N_ + n_g]
                    = f2bf(acc[r] + bvp[r]);
        } else {
            #pragma unroll
            for (int r = 0; r < 4; ++r)
                xc_bf[(size_t)(b * C2_ + (ot - 8) * 16 + quad * 4 + r) * N_ + n_g]
                    = f2bf(acc[r]);
        }
    }
}

// ---------------------------------------------------------------------------
// K2_sym: partial row softmax sums exploiting E symmetry (E[n][m]=E[m][n]
//     since q,k share w_qk).  Only tiles ti<=tj computed: 528/1024 = 51.6%
//     of E-GEMM+exp2.  Off-diag tile (ti,tj): row sums -> range ti slot tj,
//     col sums -> range tj slot ti; diag: rows only.  Every (slot,range)
//     written once -> no atomics.  part_rs[32][8][4096].  Grid 4224.
// ---------------------------------------------------------------------------
__global__ __launch_bounds__(256) void k2_sym(
    const unsigned short* __restrict__ qk_t, float* __restrict__ part_rs)
{
    __shared__ __align__(16) unsigned short slab[128 * 64];
    __shared__ float cwl[4 * 128];
    const int tid = threadIdx.x;
    const int wave = tid >> 6, lane = tid & 63;
    const int quad = lane >> 4, col = lane & 15;
    const int b = blockIdx.x & 7;
    int job = blockIdx.x >> 3, ti = 0;                 // job in [0,528)
    while (job >= 32 - ti) { job -= 32 - ti; ++ti; }
    const int tj = ti + job;
    const unsigned short* qb = qk_t + (size_t)b * N_ * C2_;

    const int n_base = ti * 128 + wave * 32;
    bf16x8 a0[2], a1[2];
    #pragma unroll
    for (int s = 0; s < 2; ++s) {
        const unsigned short* p = qb + (size_t)(n_base + s * 16 + col) * C2_ + quad * 8;
        a0[s] = *(const bf16x8*)p;
        a1[s] = *(const bf16x8*)(p + 32);
    }

    #pragma unroll
    for (int r = 0; r < 4; ++r) {
        const int idx = r * 256 + tid;                 // [0, 1024)
        const int row = idx >> 3, seg = idx & 7;
        gl_lds16(qb + (size_t)(tj * 128 + row) * C2_ + (size_t)(seg ^ (row & 7)) * 8,
                 slab + idx * 8);
    }
    __syncthreads();

    float run_s[2][4];
    #pragma unroll
    for (int s = 0; s < 2; ++s)
        #pragma unroll
        for (int r = 0; r < 4; ++r) run_s[s][r] = 0.f;

    #pragma unroll
    for (int g = 0; g < 8; ++g) {
        const int row = g * 16 + col;
        const bf16x8 b0 = *(const bf16x8*)(slab + row * 64 + ((quad ^ (col & 7)) * 8));
        const bf16x8 b1 = *(const bf16x8*)(slab + row * 64 + (((4 + quad) ^ (col & 7)) * 8));
        float cs = 0.f;
        #pragma unroll
        for (int s = 0; s < 2; ++s) {
            f32x4 acc = {0.f, 0.f, 0.f, 0.f};
            __builtin_amdgcn_s_setprio(1);
            acc = MFMA16(a0[s], b0, acc);
            acc = MFMA16(a1[s], b1, acc);
            __builtin_amdgcn_s_setprio(0);
            #pragma unroll
            for (int r = 0; r < 4; ++r) {
                const float u = __builtin_amdgcn_exp2f(acc[r]);
                run_s[s][r] += u;
                cs += u;
            }
        }
        cs += __shfl_xor(cs, 16, 64);
        cs += __shfl_xor(cs, 32, 64);
        if (quad == 0) cwl[wave * 128 + g * 16 + col] = cs;
    }
    __syncthreads();
    if (ti != tj && tid < 128) {
        const float c = cwl[tid] + cwl[128 + tid] + cwl[256 + tid] + cwl[384 + tid];
        part_rs[((size_t)(ti * 8 + b) << 12) + tj * 128 + tid] = c;
    }

    #pragma unroll
    for (int s = 0; s < 2; ++s)
        #pragma unroll
        for (int r = 0; r < 4; ++r) {
            #pragma unroll
            for (int off = 1; off < 16; off <<= 1)
                run_s[s][r] += __shfl_xor(run_s[s][r], off, 64);
        }
    if (col == 0) {
        #pragma unroll
        for (int s = 0; s < 2; ++s)
            #pragma unroll
            for (int r = 0; r < 4; ++r)
                part_rs[((size_t)(tj * 8 + b) << 12) + n_base + s * 16 + quad * 4 + r]
                    = run_s[s][r];
    }
}

// ---------------------------------------------------------------------------
// K3: R7 structure + lw via MFMA C-operand, with k2w MERGED as a prologue:
//     each block computes its own lw[n] = -log2(sum_t part_rs[t][b][n]) for
//     its 2048-n split-K range into +8KB LDS (32 coalesced loads/n, ~4us
//     aggregate L2 traffic) -- saves the k2w launch.  lwA/lwB prefetch now
//     reads LDS.  S'' = exp2(E+lw); PV raw xv; colsum A = ones.  stS stride
//     40 shorts = 80B, 16B-ALIGNED (R13: stride 42 scalarized LDS ops).
//     8 waves, 32-m/wave, split-K=2, grid 512; LDS 61440 -> 2 blk/CU.
//     launch_bounds(512,4): cap 128 >> natural ~110 -> no spill.
// ---------------------------------------------------------------------------
__global__ __launch_bounds__(512, 4) void k3_pv(
    const unsigned short* __restrict__ qk_t, const unsigned short* __restrict__ xv_bf,
    const float* __restrict__ part_rs,
    unsigned short* __restrict__ yb0, unsigned short* __restrict__ yb1,
    float* __restrict__ cspart)
{
    // 0..16K: qk dbuf | 16K..32K: xv dbuf | 32K..52K: stS | 52K..60K: lwl
    __shared__ __align__(16) unsigned char lds_raw[32768 + 8 * 2560 + 8192];
    const int tid = threadIdx.x;
    const int wave = tid >> 6, lane = tid & 63;
    const int quad = lane >> 4, col = lane & 15;
    const int nh2 = wave & 1, mh = wave >> 1;        // mh 0..3
    const int b = blockIdx.x & 7;
    const int m_blk = ((blockIdx.x >> 3) & 31) * 128;
    const int sk = blockIdx.x >> 8;                  // 0..1 (split-K index)
    const int n_start = sk * 2048;
    const int n_chunks = 32;
    const int m_wave = m_blk + mh * 32;
    const unsigned short* qb = qk_t + (size_t)b * N_ * C2_;
    const unsigned short* vb = xv_bf + (size_t)b * C2_ * N_;
    unsigned short* yp = (sk == 0) ? yb0 : yb1;

    // prologue (k2w merged): lwl[nl] = -log2(rowsum) for this block's n-range
    float* lwl = (float*)(lds_raw + 53248);          // 2048 f32 = 8 KB
    #pragma unroll
    for (int i = 0; i < 4; ++i) {
        const int nl = i * 512 + tid;                // [0, 2048)
        float s = 0.f;
        #pragma unroll
        for (int t = 0; t < 32; ++t)
            s += part_rs[((size_t)(t * 8 + b) << 12) + n_start + nl];
        lwl[nl] = -__log2f(s);
    }

    // persistent B-operands for E: this wave's 32 m-cols (2 groups of 16)
    bf16x8 kb0[2], kb1[2];
    #pragma unroll
    for (int g = 0; g < 2; ++g) {
        const unsigned short* p = qb + (size_t)(m_wave + g * 16 + col) * C2_ + quad * 8;
        kb0[g] = *(const bf16x8*)p;
        kb1[g] = *(const bf16x8*)(p + 32);
    }

    // colsum A-operand: constant ones (S'' already carries the row scale)
    bf16x8 ones;
    #pragma unroll
    for (int j = 0; j < 8; ++j) ones[j] = (__bf16)1.0f;

    unsigned short* stS = (unsigned short*)(lds_raw + 32768 + wave * 2560); // [g][col][40]

    // stage one 64n qk slab + 64ch xv tile (8 KB each): 1 DMA/lane/array
    auto stage = [&](int n0, int p) {
        unsigned char* qbase = lds_raw + p * 8192;
        unsigned char* vbase = lds_raw + 16384 + p * 8192;
        const int row = tid >> 3, seg = tid & 7;
        const int ss = seg ^ (row & 7);
        gl_lds16(qb + (size_t)(n0 + row) * C2_ + (size_t)ss * 8, qbase + tid * 16);
        gl_lds16(vb + (size_t)row * N_ + n0 + ss * 8, vbase + tid * 16);
    };

    f32x4 accY[2][4];   // [g][os]
    #pragma unroll
    for (int g = 0; g < 2; ++g)
        #pragma unroll
        for (int os = 0; os < 4; ++os) accY[g][os] = (f32x4){0.f, 0.f, 0.f, 0.f};
    f32x4 csacc[2];
    #pragma unroll
    for (int g = 0; g < 2; ++g) csacc[g] = (f32x4){0.f, 0.f, 0.f, 0.f};

    stage(n_start, 0);
    __syncthreads();                                 // lwl written + chunk 0 staged

    // lw prefetch from LDS: this wave's 8 lw values per chunk, one chunk ahead
    const float* lwp = lwl + nh2 * 32 + quad * 4;
    float4 lwA = *(const float4*)(lwp);              // chunk 0, ns=0
    float4 lwB = *(const float4*)(lwp + 16);         // chunk 0, ns=1

    for (int c = 0; c < n_chunks; ++c) {
        const int n0 = n_start + c * 64;
        const int p = c & 1;
        if (c + 1 < n_chunks) stage(n0 + 64, 1 - p);

        const unsigned short* qt = (const unsigned short*)(lds_raw + p * 8192);
        const unsigned short* vt = (const unsigned short*)(lds_raw + 16384 + p * 8192);

        // E phase; S'' = exp2(E + lw[n]) -> LDS (lw enters as MFMA C-init,
        // prefetched last chunk -> off the serial chain)
        #pragma unroll
        for (int ns = 0; ns < 2; ++ns) {
            const int row = nh2 * 32 + ns * 16 + col;
            const bf16x8 qa0 = *(const bf16x8*)(qt + row * 64 + ((quad ^ (col & 7)) * 8));
            const bf16x8 qa1 = *(const bf16x8*)(qt + row * 64 + (((4 + quad) ^ (col & 7)) * 8));
            const float4 lw4 = ns ? lwB : lwA;
            #pragma unroll
            for (int g = 0; g < 2; ++g) {
                f32x4 acc = {lw4.x, lw4.y, lw4.z, lw4.w};
                acc = MFMA16(qa0, kb0[g], acc);
                acc = MFMA16(qa1, kb1[g], acc);
                union { unsigned short us[4]; uint2 u2; } pk;
                #pragma unroll
                for (int r = 0; r < 4; ++r)
                    pk.us[r] = f2bf(__builtin_amdgcn_exp2f(acc[r]));
                *(uint2*)&stS[(g * 16 + col) * 40 + ns * 16 + quad * 4] = pk.u2;
            }
        }

        // prefetch lw for next chunk (cheap LDS reads, covered by PV below)
        if (c + 1 < n_chunks) {
            lwA = *(const float4*)(lwp + (c + 1) * 64);
            lwB = *(const float4*)(lwp + (c + 1) * 64 + 16);
        }

        // same-wave round-trip: S'' as B-operand (K = this wave's 32 n)
        bf16x8 sB[2];
        #pragma unroll
        for (int g = 0; g < 2; ++g)
            sB[g] = *(const bf16x8*)&stS[(g * 16 + col) * 40 + quad * 8];

        // colsum via MFMA with A = ones -> D rows all = colsum of S''
        #pragma unroll
        for (int g = 0; g < 2; ++g)
            csacc[g] = MFMA16(ones, sB[g], csacc[g]);

        // PV: A = raw xv rows (o), k = this wave's 32 n
        #pragma unroll
        for (int os = 0; os < 4; ++os) {
            const bf16x8 va = *(const bf16x8*)(vt + (os * 16 + col) * 64 +
                                               (((nh2 * 4 + quad) ^ (col & 7)) * 8));
            #pragma unroll
            for (int g = 0; g < 2; ++g)
                accY[g][os] = MFMA16(va, sB[g], accY[g][os]);
        }
        __syncthreads();
    }

    // epilogue: combine the two n-halves (waves nh2=1 -> LDS; nh2=0 adds+writes)
    float* cmb = (float*)lds_raw;              // 32 KB: [mh][g*4+os][r][lane]
    float* csc = (float*)(lds_raw + 32768);    // 2 KB:  [mh][g][lane]
    if (nh2 == 1) {
        #pragma unroll
        for (int g = 0; g < 2; ++g) {
            #pragma unroll
            for (int os = 0; os < 4; ++os)
                #pragma unroll
                for (int r = 0; r < 4; ++r)
                    cmb[((mh * 8 + g * 4 + os) * 4 + r) * 64 + lane] = accY[g][os][r];
            csc[(mh * 2 + g) * 64 + lane] = csacc[g][0];
        }
    }
    __syncthreads();
    if (nh2 == 0) {
        #pragma unroll
        for (int g = 0; g < 2; ++g) {
            const float cs = csacc[g][0] + csc[(mh * 2 + g) * 64 + lane];
            if (lane < 16)
                cspart[((size_t)sk * 8 + b) * N_ + m_wave + g * 16 + lane] = cs;
            #pragma unroll
            for (int os = 0; os < 4; ++os)
                #pragma unroll
                for (int r = 0; r < 4; ++r) {
                    const float v = accY[g][os][r] +
                        cmb[((mh * 8 + g * 4 + os) * 4 + r) * 64 + lane];
                    yp[(size_t)(b * C2_ + os * 16 + quad * 4 + r) * N_ + m_wave + g * 16 + col]
                        = f2bf(v);
                }
        }
    }
}

// ---------------------------------------------------------------------------
// K4: fused partial-combine + w_t GEMM (MFMA) + BN partial stats.
//     Grid (64, 8).  cinv = 1/(eps+sum cspart); d = xc - (y0+y1)*cinv
//     (xc BF16) staged TRANSPOSED to LDS bf16 d_t[n][72]; w_t [o][72].
//     Wave = o-tile; K=64.  t -> t_bf (BF16; stats from unrounded f32);
//     per-block channel partials -> part_bn[c][blk] (streaming writes --
//     R14 LESSON: 512-block atomicAdd to a 512B bn region serializes
//     cross-XCD at the fabric, +45us; never contend atomics on hot lines).
// ---------------------------------------------------------------------------
__global__ __launch_bounds__(256) void k4_t(
    const unsigned short* __restrict__ xc_bf, const unsigned short* __restrict__ y0,
    const unsigned short* __restrict__ y1,
    const float* __restrict__ cspart, const float* __restrict__ w_t,
    const float* __restrict__ b_t, unsigned short* __restrict__ t_bf,
    float* __restrict__ part_bn)
{
    __shared__ __align__(16) unsigned short wlds[64 * 72];
    __shared__ __align__(16) unsigned short d_t[64 * 72];
    __shared__ float cinv[64];
    const int tid = threadIdx.x;
    const int wave = tid >> 6, lane = tid & 63;
    const int quad = lane >> 4, col = lane & 15;
    const int b = blockIdx.y;
    const int n0 = blockIdx.x * 64;
    const size_t base = (size_t)b * C2_ * N_;

    #pragma unroll
    for (int it = 0; it < 4; ++it) {
        const int idx4 = it * 256 + tid;               // [0, 1024)
        const int o = idx4 >> 4, i4 = (idx4 & 15) * 4;
        const float4 v = *(const float4*)(w_t + o * 64 + i4);
        us4 pk;
        pk.a = f2bf(v.x); pk.b = f2bf(v.y); pk.c = f2bf(v.z); pk.d = f2bf(v.w);
        *(us4*)&wlds[o * 72 + i4] = pk;
    }
    if (tid < 64) {
        const int n = n0 + tid;
        const float cs = cspart[(size_t)b * N_ + n] + cspart[(size_t)(8 + b) * N_ + n];
        cinv[tid] = 1.0f / (1e-9f + cs);
    }
    __syncthreads();

    #pragma unroll
    for (int it = 0; it < 4; ++it) {
        const int idx4 = it * 256 + tid;               // [0, 1024)
        const int i = idx4 >> 4, n4 = (idx4 & 15) * 4;
        const size_t g = base + (size_t)i * N_ + n0 + n4;
        const us4 cx = *(const us4*)(xc_bf + g);
        const us4 u0 = *(const us4*)(y0 + g);
        const us4 u1 = *(const us4*)(y1 + g);
        d_t[(n4 + 0) * 72 + i] = f2bf(bf2f(cx.a) - (bf2f(u0.a) + bf2f(u1.a)) * cinv[n4 + 0]);
        d_t[(n4 + 1) * 72 + i] = f2bf(bf2f(cx.b) - (bf2f(u0.b) + bf2f(u1.b)) * cinv[n4 + 1]);
        d_t[(n4 + 2) * 72 + i] = f2bf(bf2f(cx.c) - (bf2f(u0.c) + bf2f(u1.c)) * cinv[n4 + 2]);
        d_t[(n4 + 3) * 72 + i] = f2bf(bf2f(cx.d) - (bf2f(u0.d) + bf2f(u1.d)) * cinv[n4 + 3]);
    }
    __syncthreads();

    const int ow = wave * 16;
    bf16x8 afr[2];
    #pragma unroll
    for (int kt = 0; kt < 2; ++kt)
        afr[kt] = *(const bf16x8*)&wlds[(ow + col) * 72 + kt * 32 + quad * 8];
    const float4 bt4 = *(const float4*)(b_t + ow + quad * 4);
    const float* btp = (const float*)&bt4;

    float s[4] = {0.f, 0.f, 0.f, 0.f}, q2[4] = {0.f, 0.f, 0.f, 0.f};
    #pragma unroll
    for (int ns = 0; ns < 4; ++ns) {
        f32x4 acc = {0.f, 0.f, 0.f, 0.f};
        #pragma unroll
        for (int kt = 0; kt < 2; ++kt) {
            const bf16x8 bfr = *(const bf16x8*)&d_t[(ns * 16 + col) * 72 + kt * 32 + quad * 8];
            acc = MFMA16(afr[kt], bfr, acc);
        }
        #pragma unroll
        for (int r = 0; r < 4; ++r) {
            const float t = acc[r] + btp[r];
            t_bf[base + (size_t)(ow + quad * 4 + r) * N_ + n0 + ns * 16 + col] = f2bf(t);
            s[r] += t;
            q2[r] += t * t;
        }
    }
    #pragma unroll
    for (int r = 0; r < 4; ++r) {
        #pragma unroll
        for (int off = 1; off < 16; off <<= 1) {
            s[r]  += __shfl_xor(s[r],  off, 64);
            q2[r] += __shfl_xor(q2[r], off, 64);
        }
    }
    if (col == 0) {
        const int blk = blockIdx.x * 8 + b;            // [0, 512)
        #pragma unroll
        for (int r = 0; r < 4; ++r) {
            part_bn[(size_t)(ow + quad * 4 + r) * 512 + blk]      = s[r];
            part_bn[(size_t)(64 + ow + quad * 4 + r) * 512 + blk] = q2[r];
        }
    }
}

// ---------------------------------------------------------------------------
// K6: out = xc + relu(gamma * (t - mean) * rsqrt(var + eps) + beta)
//     k5r MERGED: each block reduces its channel's 512 part_bn partials
//     itself (4 KB L2 reads, redundant x32 across blocks -- 8 MB total).
//     o is block-uniform: blocks span 256 float4 = quarter of an o-row.
// ---------------------------------------------------------------------------
__global__ __launch_bounds__(256) void k6_out(
    const unsigned short* __restrict__ xc_bf, const unsigned short* __restrict__ t_bf,
    const float* __restrict__ part_bn, const float* __restrict__ gamma,
    const float* __restrict__ beta, float* __restrict__ out)
{
    __shared__ float red[8];
    const int tid = threadIdx.x, wave = tid >> 6, lane = tid & 63;
    const int o = ((blockIdx.x * 256) >> 10) & 63;     // block-uniform channel
    float s = 0.f, q = 0.f;
    #pragma unroll
    for (int j = tid; j < 512; j += 256) {
        s += part_bn[(size_t)o * 512 + j];
        q += part_bn[(size_t)(64 + o) * 512 + j];
    }
    #pragma unroll
    for (int off = 1; off < 64; off <<= 1) {
        s += __shfl_xor(s, off, 64);
        q += __shfl_xor(q, off, 64);
    }
    if (lane == 0) { red[wave] = s; red[4 + wave] = q; }
    __syncthreads();
    const float sum = red[0] + red[1] + red[2] + red[3];
    const float sq  = red[4] + red[5] + red[6] + red[7];

    const int idx = blockIdx.x * 256 + tid;
    const float invC = 1.0f / (float)(B_ * N_);
    const float mean = sum * invC;
    const float var  = sq * invC - mean * mean;
    const float sc = gamma[o] * rsqrtf(var + 1e-5f);
    const float sh = beta[o] - mean * sc;
    const us4 t4 = ((const us4*)t_bf)[idx];
    const us4 c4 = ((const us4*)xc_bf)[idx];
    float4 r;
    r.x = bf2f(c4.a) + fmaxf(0.f, sc * bf2f(t4.a) + sh);
    r.y = bf2f(c4.b) + fmaxf(0.f, sc * bf2f(t4.b) + sh);
    r.z = bf2f(c4.c) + fmaxf(0.f, sc * bf2f(t4.c) + sh);
    r.w = bf2f(c4.d) + fmaxf(0.f, sc * bf2f(t4.d) + sh);
    ((float4*)out)[idx] = r;
}

extern "C" void kernel_launch(void* const* d_in, const int* in_sizes, int n_in,
                              void* d_out, int out_size, void* d_ws, size_t ws_size,
                              hipStream_t stream) {
    const float* x     = (const float*)d_in[0];
    const float* w_qk  = (const float*)d_in[1];
    const float* w_v   = (const float*)d_in[2];
    const float* b_v   = (const float*)d_in[3];
    const float* w_x   = (const float*)d_in[4];
    const float* w_t   = (const float*)d_in[5];
    const float* b_t   = (const float*)d_in[6];
    const float* gamma = (const float*)d_in[7];
    const float* beta  = (const float*)d_in[8];
    float* out = (float*)d_out;

    char* ws = (char*)d_ws;
    unsigned short* qk_t  = (unsigned short*)ws;                      // 4 MB
    unsigned short* xv_bf = (unsigned short*)(ws + (4  << 20));       // 4 MB
    unsigned short* xc_bf = (unsigned short*)(ws + (8  << 20));       // 4 MB (bf16)
    unsigned short* t_bf  = (unsigned short*)(ws + (12 << 20));       // 4 MB (bf16)
    unsigned short* yb0 = (unsigned short*)(ws + (16 << 20));         // 4 MB (bf16 partial Y)
    unsigned short* yb1 = (unsigned short*)(ws + (20 << 20));         // 4 MB (bf16 partial Y)
    float* part_rs = (float*)(ws + (24 << 20));                       // 4 MB (k2_sym -> k3)
    float* cspart  = (float*)(ws + (32 << 20));                       // 256 KB (k3 -> k4)
    float* part_bn = (float*)(ws + (33 << 20));                       // 256 KB (k4 -> k6)

    hipLaunchKernelGGL(k1_proj,     dim3(64, 8),  256, 0, stream,
                       x, w_qk, w_v, b_v, w_x, qk_t, xv_bf, xc_bf);
    hipLaunchKernelGGL(k2_sym,      dim3(4224),   256, 0, stream, qk_t, part_rs);
    hipLaunchKernelGGL(k3_pv,       dim3(512),    512, 0, stream,
                       qk_t, xv_bf, part_rs, yb0, yb1, cspart);
    hipLaunchKernelGGL(k4_t,        dim3(64, 8),  256, 0, stream,
                       xc_bf, yb0, yb1, cspart, w_t, b_t, t_bf, part_bn);
    hipLaunchKernelGGL(k6_out,      dim3(2048),   256, 0, stream, xc_bf, t_bf, part_bn, gamma, beta, out);
}